// Round 3
// baseline (1612.930 us; speedup 1.0000x reference)
//
#include <hip/hip_runtime.h>
#include <cstdint>
#include <cstddef>

// ---------------------------------------------------------------------------
// GCN forward:
//   deg -> cs/cd/deg_idx -> CSR(dst) -> WF=proj_W@W1mid -> h1 = cs*(x@W1)
//   -> agg1 (gather-sum by dst) -> y = relu(agg1*cd + b1)
//   -> h2 = cs*(y@W2) -> agg2 -> out = agg2*cd + b2
// x = [logits | features@proj_W + proj_b | deg_table[deg_idx]] is never
// materialized: its W1 product is computed as 40 BK=16 k-tiles drawn from
// features/WF, logits/W1[0:64], deg_emb/W1[192:256].
// GEMM inner loop is pure LDS+FMA: BOTH A and B tiles are staged in LDS via
// a register-prefetch pipeline (store -> sync -> prefetch t+1 -> compute ->
// sync), so no global load sits on the kk critical path. Round-2 lesson:
// per-kk global B loads stall on vmcnt at ~L1 latency (VALUBusy 32%), and a
// column-split doubles A HBM traffic (FETCH 121->490 MB) - both reverted.
// ---------------------------------------------------------------------------

__global__ __launch_bounds__(256) void k_degrees(
    const int* __restrict__ src, const int* __restrict__ dst, int E,
    int* __restrict__ outd, int* __restrict__ ind)
{
    int i = blockIdx.x * 256 + threadIdx.x;
    if (i < E) {
        atomicAdd(&outd[src[i]], 1);
        atomicAdd(&ind[dst[i]], 1);
    }
}

__global__ __launch_bounds__(256) void k_norms(
    const int* __restrict__ outd, const int* __restrict__ ind, int N,
    float* __restrict__ cs, float* __restrict__ cd, int* __restrict__ didx)
{
    int i = blockIdx.x * 256 + threadIdx.x;
    if (i < N) {
        int od = outd[i], id = ind[i];
        cs[i] = rsqrtf((float)(od > 0 ? od : 1));
        cd[i] = rsqrtf((float)(id > 0 ? id : 1));
        int d = od + id;
        didx[i] = d > 511 ? 511 : d;
    }
}

// Single-block exclusive scan of in-degrees -> row_ptr, cursor
__global__ __launch_bounds__(1024) void k_scan(
    const int* __restrict__ ind, int N,
    int* __restrict__ rowp, int* __restrict__ cursor)
{
    __shared__ int sums[1024];
    int t = threadIdx.x;
    int chunk = (N + 1023) >> 10;
    int b = t * chunk, e = b + chunk;
    if (b > N) b = N;
    if (e > N) e = N;
    int s = 0;
    for (int i = b; i < e; ++i) s += ind[i];
    sums[t] = s;
    __syncthreads();
    for (int off = 1; off < 1024; off <<= 1) {
        int v = (t >= off) ? sums[t - off] : 0;
        __syncthreads();
        sums[t] += v;
        __syncthreads();
    }
    int run = (t == 0) ? 0 : sums[t - 1];
    for (int i = b; i < e; ++i) {
        rowp[i] = run;
        cursor[i] = run;
        run += ind[i];
    }
    if (t == 1023) rowp[N] = sums[1023];
}

__global__ __launch_bounds__(256) void k_csrfill(
    const int* __restrict__ src, const int* __restrict__ dst, int E,
    int* __restrict__ cursor, int* __restrict__ csr)
{
    int i = blockIdx.x * 256 + threadIdx.x;
    if (i < E) {
        int pos = atomicAdd(&cursor[dst[i]], 1);
        csr[pos] = src[i];
    }
}

// WF[k][j] = sum_m proj_W[k][m] * W1[64+m][j]   (512x128)
__global__ __launch_bounds__(256) void k_wf(
    const float* __restrict__ projW, const float* __restrict__ W1,
    float* __restrict__ WF)
{
    int idx = blockIdx.x * 256 + threadIdx.x;
    int k = idx >> 7, j = idx & 127;
    const float* a = projW + (size_t)k * 128;
    float s = 0.f;
#pragma unroll 8
    for (int m = 0; m < 128; ++m) s = fmaf(a[m], W1[(size_t)(64 + m) * 128 + j], s);
    WF[idx] = s;
}

// cb[j] = sum_m proj_b[m] * W1[64+m][j]
__global__ void k_cb(const float* __restrict__ projb, const float* __restrict__ W1,
                     float* __restrict__ cb)
{
    int j = threadIdx.x;
    float s = 0.f;
    for (int m = 0; m < 128; ++m) s = fmaf(projb[m], W1[(size_t)(64 + m) * 128 + j], s);
    cb[j] = s;
}

// ---- k_h1 helpers: 40 virtual k-tiles over 3 A/B sources ----
__device__ __forceinline__ const float* h1_a_src(
    int t, int node, int didxn,
    const float* features, const float* logits, const float* deg_table)
{
    if (t < 32) return features + (size_t)node * 512 + t * 16;
    if (t < 36) return logits + (size_t)node * 64 + (t - 32) * 16;
    return deg_table + (size_t)didxn * 64 + (t - 36) * 16;
}

__device__ __forceinline__ const float* h1_b_src(
    int t, const float* WF, const float* W1)
{
    // Row pointer of the 16x128 B tile; tile is a contiguous 8 KB block
    // (row stride == tile width == 128 floats).
    if (t < 32) return WF + (size_t)t * 16 * 128;
    if (t < 36) return W1 + (size_t)(t - 32) * 16 * 128;
    return W1 + (size_t)(192 + (t - 36) * 16) * 128;
}

// BM=128, BN=128, BK=16, 256 threads, 8x8 microtile. A and B both in LDS.
__global__ __launch_bounds__(256, 4) void k_h1(
    const float* __restrict__ logits, const float* __restrict__ features,
    const float* __restrict__ deg_table, const int* __restrict__ didx,
    const float* __restrict__ WF, const float* __restrict__ W1,
    const float* __restrict__ cb, const float* __restrict__ cs,
    float* __restrict__ h1, int N)
{
    constexpr int BK = 16, NT = 40;
    __shared__ float As[BK][132];   // [kk][row], +4 pad
    __shared__ float Bs[BK][128];   // [kk][col], contiguous 8 KB
    int tid = threadIdx.x;
    int i0 = blockIdx.x * 128;
    int trow = tid >> 4, tcol = tid & 15;
    int la_row = tid >> 2;              // 0..63
    int la_k4 = (tid & 3) * 4;          // 0,4,8,12
    int nodeA0 = i0 + la_row;       if (nodeA0 >= N) nodeA0 = N - 1;
    int nodeA1 = i0 + la_row + 64;  if (nodeA1 >= N) nodeA1 = N - 1;
    int didx0 = didx[nodeA0];
    int didx1 = didx[nodeA1];
    float* BsFlat = &Bs[0][0];

    float acc[8][8];
#pragma unroll
    for (int r = 0; r < 8; ++r)
#pragma unroll
        for (int c = 0; c < 8; ++c) acc[r][c] = 0.f;

    // prologue: prefetch tile 0 (A: 2x float4, B: 2x float4 of the 8KB tile)
    float4 ra0 = *(const float4*)(h1_a_src(0, nodeA0, didx0, features, logits, deg_table) + la_k4);
    float4 ra1 = *(const float4*)(h1_a_src(0, nodeA1, didx1, features, logits, deg_table) + la_k4);
    {
        const float* b0 = h1_b_src(0, WF, W1);
        float4 t0 = *(const float4*)(b0 + tid * 4);
        float4 t1 = *(const float4*)(b0 + 1024 + tid * 4);
        // keep in named regs via direct use below
        *(float4*)(BsFlat + tid * 4) = t0;          // first store happens pre-loop
        *(float4*)(BsFlat + 1024 + tid * 4) = t1;
        As[la_k4 + 0][la_row] = ra0.x;
        As[la_k4 + 1][la_row] = ra0.y;
        As[la_k4 + 2][la_row] = ra0.z;
        As[la_k4 + 3][la_row] = ra0.w;
        As[la_k4 + 0][la_row + 64] = ra1.x;
        As[la_k4 + 1][la_row + 64] = ra1.y;
        As[la_k4 + 2][la_row + 64] = ra1.z;
        As[la_k4 + 3][la_row + 64] = ra1.w;
    }

    float4 rb0, rb1;
    for (int t = 0; t < NT; ++t) {
        __syncthreads();
        if (t + 1 < NT) {
            ra0 = *(const float4*)(h1_a_src(t + 1, nodeA0, didx0, features, logits, deg_table) + la_k4);
            ra1 = *(const float4*)(h1_a_src(t + 1, nodeA1, didx1, features, logits, deg_table) + la_k4);
            const float* bn = h1_b_src(t + 1, WF, W1);
            rb0 = *(const float4*)(bn + tid * 4);
            rb1 = *(const float4*)(bn + 1024 + tid * 4);
        }
#pragma unroll
        for (int kk = 0; kk < BK; ++kk) {
            float4 av0 = *(const float4*)&As[kk][trow * 8];
            float4 av1 = *(const float4*)&As[kk][trow * 8 + 4];
            float4 bv0 = *(const float4*)&Bs[kk][tcol * 8];
            float4 bv1 = *(const float4*)&Bs[kk][tcol * 8 + 4];
            float a_[8] = {av0.x, av0.y, av0.z, av0.w, av1.x, av1.y, av1.z, av1.w};
            float b_[8] = {bv0.x, bv0.y, bv0.z, bv0.w, bv1.x, bv1.y, bv1.z, bv1.w};
#pragma unroll
            for (int r = 0; r < 8; ++r)
#pragma unroll
                for (int c = 0; c < 8; ++c)
                    acc[r][c] = fmaf(a_[r], b_[c], acc[r][c]);
        }
        __syncthreads();
        if (t + 1 < NT) {
            As[la_k4 + 0][la_row] = ra0.x;
            As[la_k4 + 1][la_row] = ra0.y;
            As[la_k4 + 2][la_row] = ra0.z;
            As[la_k4 + 3][la_row] = ra0.w;
            As[la_k4 + 0][la_row + 64] = ra1.x;
            As[la_k4 + 1][la_row + 64] = ra1.y;
            As[la_k4 + 2][la_row + 64] = ra1.z;
            As[la_k4 + 3][la_row + 64] = ra1.w;
            *(float4*)(BsFlat + tid * 4) = rb0;
            *(float4*)(BsFlat + 1024 + tid * 4) = rb1;
        }
    }

    int col0 = tcol * 8;
    float4 cbv0 = *(const float4*)(cb + col0);
    float4 cbv1 = *(const float4*)(cb + col0 + 4);
#pragma unroll
    for (int r = 0; r < 8; ++r) {
        int node = i0 + trow * 8 + r;
        if (node < N) {
            float sc = cs[node];
            float4 o0, o1;
            o0.x = sc * (acc[r][0] + cbv0.x);
            o0.y = sc * (acc[r][1] + cbv0.y);
            o0.z = sc * (acc[r][2] + cbv0.z);
            o0.w = sc * (acc[r][3] + cbv0.w);
            o1.x = sc * (acc[r][4] + cbv1.x);
            o1.y = sc * (acc[r][5] + cbv1.y);
            o1.z = sc * (acc[r][6] + cbv1.z);
            o1.w = sc * (acc[r][7] + cbv1.w);
            *(float4*)(h1 + (size_t)node * 128 + col0) = o0;
            *(float4*)(h1 + (size_t)node * 128 + col0 + 4) = o1;
        }
    }
}

// Layer-1 aggregation: y[i] = relu( (sum_{e: dst=i} h1[src_e]) * cd[i] + b1 )
__global__ __launch_bounds__(256) void k_agg1(
    const float* __restrict__ h1, const int* __restrict__ rowp,
    const int* __restrict__ csr, const float* __restrict__ cd,
    const float* __restrict__ b1, float* __restrict__ y, int N)
{
    int i = blockIdx.x * 4 + (threadIdx.x >> 6);
    if (i >= N) return;
    int lane = threadIdx.x & 63;
    int s0 = rowp[i], s1 = rowp[i + 1];
    float ax = 0.f, ay = 0.f;
    int e = s0;
    for (; e + 4 <= s1; e += 4) {
        int j0 = csr[e], j1 = csr[e + 1], j2 = csr[e + 2], j3 = csr[e + 3];
        float2 v0 = *(const float2*)(h1 + (size_t)j0 * 128 + lane * 2);
        float2 v1 = *(const float2*)(h1 + (size_t)j1 * 128 + lane * 2);
        float2 v2 = *(const float2*)(h1 + (size_t)j2 * 128 + lane * 2);
        float2 v3 = *(const float2*)(h1 + (size_t)j3 * 128 + lane * 2);
        ax += (v0.x + v1.x) + (v2.x + v3.x);
        ay += (v0.y + v1.y) + (v2.y + v3.y);
    }
    for (; e < s1; ++e) {
        int j = csr[e];
        float2 v = *(const float2*)(h1 + (size_t)j * 128 + lane * 2);
        ax += v.x; ay += v.y;
    }
    float cdi = cd[i];
    float2 o;
    o.x = fmaxf(fmaf(ax, cdi, b1[lane * 2 + 0]), 0.f);
    o.y = fmaxf(fmaf(ay, cdi, b1[lane * 2 + 1]), 0.f);
    *(float2*)(y + (size_t)i * 128 + lane * 2) = o;
}

// h2 = cs * (y @ W2)   M=100K, N=64, K=128; A and B both in LDS.
__global__ __launch_bounds__(256, 4) void k_h2(
    const float* __restrict__ y, const float* __restrict__ W2,
    const float* __restrict__ cs, float* __restrict__ h2, int N)
{
    constexpr int BK = 16, NT = 8;
    __shared__ float As[BK][132];
    __shared__ float Bs[BK][64];    // contiguous 4 KB
    int tid = threadIdx.x;
    int i0 = blockIdx.x * 128;
    int trow = tid >> 4, tcol = tid & 15;
    int la_row = tid >> 2;
    int la_k4 = (tid & 3) * 4;
    int n0 = i0 + la_row;      if (n0 >= N) n0 = N - 1;
    int n1 = i0 + la_row + 64; if (n1 >= N) n1 = N - 1;
    const float* a0 = y + (size_t)n0 * 128 + la_k4;
    const float* a1 = y + (size_t)n1 * 128 + la_k4;
    float* BsFlat = &Bs[0][0];

    float acc[8][4];
#pragma unroll
    for (int r = 0; r < 8; ++r)
#pragma unroll
        for (int c = 0; c < 4; ++c) acc[r][c] = 0.f;

    float4 ra0 = *(const float4*)(a0);
    float4 ra1 = *(const float4*)(a1);
    {
        float4 t0 = *(const float4*)(W2 + tid * 4);
        *(float4*)(BsFlat + tid * 4) = t0;
        As[la_k4 + 0][la_row] = ra0.x;
        As[la_k4 + 1][la_row] = ra0.y;
        As[la_k4 + 2][la_row] = ra0.z;
        As[la_k4 + 3][la_row] = ra0.w;
        As[la_k4 + 0][la_row + 64] = ra1.x;
        As[la_k4 + 1][la_row + 64] = ra1.y;
        As[la_k4 + 2][la_row + 64] = ra1.z;
        As[la_k4 + 3][la_row + 64] = ra1.w;
    }

    float4 rb0;
    for (int t = 0; t < NT; ++t) {
        __syncthreads();
        if (t + 1 < NT) {
            ra0 = *(const float4*)(a0 + (t + 1) * BK);
            ra1 = *(const float4*)(a1 + (t + 1) * BK);
            rb0 = *(const float4*)(W2 + (size_t)(t + 1) * BK * 64 + tid * 4);
        }
#pragma unroll
        for (int kk = 0; kk < BK; ++kk) {
            float4 av0 = *(const float4*)&As[kk][trow * 8];
            float4 av1 = *(const float4*)&As[kk][trow * 8 + 4];
            float4 bv = *(const float4*)&Bs[kk][tcol * 4];
            float a_[8] = {av0.x, av0.y, av0.z, av0.w, av1.x, av1.y, av1.z, av1.w};
            float b_[4] = {bv.x, bv.y, bv.z, bv.w};
#pragma unroll
            for (int r = 0; r < 8; ++r)
#pragma unroll
                for (int c = 0; c < 4; ++c)
                    acc[r][c] = fmaf(a_[r], b_[c], acc[r][c]);
        }
        __syncthreads();
        if (t + 1 < NT) {
            As[la_k4 + 0][la_row] = ra0.x;
            As[la_k4 + 1][la_row] = ra0.y;
            As[la_k4 + 2][la_row] = ra0.z;
            As[la_k4 + 3][la_row] = ra0.w;
            As[la_k4 + 0][la_row + 64] = ra1.x;
            As[la_k4 + 1][la_row + 64] = ra1.y;
            As[la_k4 + 2][la_row + 64] = ra1.z;
            As[la_k4 + 3][la_row + 64] = ra1.w;
            *(float4*)(BsFlat + tid * 4) = rb0;
        }
    }

#pragma unroll
    for (int r = 0; r < 8; ++r) {
        int node = i0 + trow * 8 + r;
        if (node < N) {
            float sc = cs[node];
            float4 o;
            o.x = sc * acc[r][0];
            o.y = sc * acc[r][1];
            o.z = sc * acc[r][2];
            o.w = sc * acc[r][3];
            *(float4*)(h2 + (size_t)node * 64 + tcol * 4) = o;
        }
    }
}

// Layer-2 aggregation: out[i] = (sum h2[src_e]) * cd[i] + b2
__global__ __launch_bounds__(256) void k_agg2(
    const float* __restrict__ h2, const int* __restrict__ rowp,
    const int* __restrict__ csr, const float* __restrict__ cd,
    const float* __restrict__ b2, float* __restrict__ out, int N)
{
    int i = blockIdx.x * 4 + (threadIdx.x >> 6);
    if (i >= N) return;
    int lane = threadIdx.x & 63;
    int s0 = rowp[i], s1 = rowp[i + 1];
    float a = 0.f;
    int e = s0;
    for (; e + 4 <= s1; e += 4) {
        int j0 = csr[e], j1 = csr[e + 1], j2 = csr[e + 2], j3 = csr[e + 3];
        float v0 = h2[(size_t)j0 * 64 + lane];
        float v1 = h2[(size_t)j1 * 64 + lane];
        float v2 = h2[(size_t)j2 * 64 + lane];
        float v3 = h2[(size_t)j3 * 64 + lane];
        a += (v0 + v1) + (v2 + v3);
    }
    for (; e < s1; ++e) a += h2[(size_t)csr[e] * 64 + lane];
    out[(size_t)i * 64 + lane] = fmaf(a, cd[i], b2[lane]);
}

extern "C" void kernel_launch(void* const* d_in, const int* in_sizes, int n_in,
                              void* d_out, int out_size, void* d_ws, size_t ws_size,
                              hipStream_t stream)
{
    const int* src = (const int*)d_in[0];
    const int* dst = (const int*)d_in[1];
    const float* logits = (const float*)d_in[2];
    const float* features = (const float*)d_in[3];
    const float* projW = (const float*)d_in[4];
    const float* projb = (const float*)d_in[5];
    const float* deg_table = (const float*)d_in[6];
    const float* W1 = (const float*)d_in[7];
    const float* b1 = (const float*)d_in[8];
    const float* W2 = (const float*)d_in[9];
    const float* b2 = (const float*)d_in[10];
    const int E = in_sizes[0];
    const int N = in_sizes[2] / 64;

    char* base = (char*)d_ws;
    size_t off = 0;
    auto alloc = [&](size_t bytes) -> void* {
        void* p = base + off;
        off += (bytes + 255) & ~(size_t)255;
        return p;
    };
    int* outd   = (int*)alloc((size_t)N * 4);
    int* ind    = (int*)alloc((size_t)N * 4);
    int* rowp   = (int*)alloc((size_t)(N + 1) * 4);
    int* cursor = (int*)alloc((size_t)N * 4);
    int* csr    = (int*)alloc((size_t)E * 4);
    int* didx   = (int*)alloc((size_t)N * 4);
    float* cs   = (float*)alloc((size_t)N * 4);
    float* cd   = (float*)alloc((size_t)N * 4);
    float* WF   = (float*)alloc((size_t)512 * 128 * 4);
    float* cb   = (float*)alloc((size_t)128 * 4);
    float* h1   = (float*)alloc((size_t)N * 128 * 4);
    float* yb   = (float*)alloc((size_t)N * 128 * 4);
    float* h2   = h1;   // h1 dead after k_agg1; reuse
    float* outp = (float*)d_out;

    hipMemsetAsync(outd, 0, (size_t)N * 4, stream);
    hipMemsetAsync(ind, 0, (size_t)N * 4, stream);

    int eb = (E + 255) / 256;
    int nb = (N + 255) / 256;
    int mb = (N + 127) / 128;

    k_degrees<<<eb, 256, 0, stream>>>(src, dst, E, outd, ind);
    k_norms<<<nb, 256, 0, stream>>>(outd, ind, N, cs, cd, didx);
    k_scan<<<1, 1024, 0, stream>>>(ind, N, rowp, cursor);
    k_csrfill<<<eb, 256, 0, stream>>>(src, dst, E, cursor, csr);
    k_wf<<<256, 256, 0, stream>>>(projW, W1, WF);
    k_cb<<<1, 128, 0, stream>>>(projb, W1, cb);
    k_h1<<<mb, 256, 0, stream>>>(logits, features, deg_table, didx, WF, W1, cb, cs, h1, N);
    k_agg1<<<(N + 3) / 4, 256, 0, stream>>>(h1, rowp, csr, cd, b1, yb, N);
    k_h2<<<mb, 256, 0, stream>>>(yb, W2, cs, h2, N);
    k_agg2<<<(N + 3) / 4, 256, 0, stream>>>(h2, rowp, csr, cd, b2, outp, N);
}

// Round 4
// 980.390 us; speedup vs baseline: 1.6452x; 1.6452x over previous
//
#include <hip/hip_runtime.h>
#include <cstdint>
#include <cstddef>

// ---------------------------------------------------------------------------
// GCN forward:
//   deg -> cs/cd/deg_idx -> CSR(dst) -> WF=proj_W@W1mid -> h1 = cs*(x@W1)
//   -> agg1 (gather-sum by dst) -> y = relu(agg1*cd + b1)
//   -> h2 = cs*(y@W2) -> agg2 -> out = agg2*cd + b2
// x = [logits | features@proj_W + proj_b | deg_table[deg_idx]] never
// materialized; its W1 product = 40 BK=16 k-tiles from features/WF,
// logits/W1[0:64], deg_emb/W1[192:256].
// GEMM inner loop is pure LDS+FMA (A and B staged via register-prefetch).
// R3 lesson: __launch_bounds__(256,4) forced 64-VGPR cap -> acc spilled to
// scratch (WRITE_SIZE 844 MB for a 51 MB output). Keep (256,2).
// h1/h2 are stored as bf16 (math stays fp32): halves the SpMM gather bytes.
// ---------------------------------------------------------------------------

__device__ __forceinline__ unsigned short f2bf(float f) {
    unsigned u = __float_as_uint(f);
    u += 0x7fff + ((u >> 16) & 1);   // round-to-nearest-even
    return (unsigned short)(u >> 16);
}
__device__ __forceinline__ float bf2f(unsigned short s) {
    return __uint_as_float(((unsigned)s) << 16);
}

__global__ __launch_bounds__(256) void k_degrees(
    const int* __restrict__ src, const int* __restrict__ dst, int E,
    int* __restrict__ outd, int* __restrict__ ind)
{
    int i = blockIdx.x * 256 + threadIdx.x;
    if (i < E) {
        atomicAdd(&outd[src[i]], 1);
        atomicAdd(&ind[dst[i]], 1);
    }
}

__global__ __launch_bounds__(256) void k_norms(
    const int* __restrict__ outd, const int* __restrict__ ind, int N,
    float* __restrict__ cs, float* __restrict__ cd, int* __restrict__ didx)
{
    int i = blockIdx.x * 256 + threadIdx.x;
    if (i < N) {
        int od = outd[i], id = ind[i];
        cs[i] = rsqrtf((float)(od > 0 ? od : 1));
        cd[i] = rsqrtf((float)(id > 0 ? id : 1));
        int d = od + id;
        didx[i] = d > 511 ? 511 : d;
    }
}

// Single-block exclusive scan of in-degrees -> row_ptr, cursor
__global__ __launch_bounds__(1024) void k_scan(
    const int* __restrict__ ind, int N,
    int* __restrict__ rowp, int* __restrict__ cursor)
{
    __shared__ int sums[1024];
    int t = threadIdx.x;
    int chunk = (N + 1023) >> 10;
    int b = t * chunk, e = b + chunk;
    if (b > N) b = N;
    if (e > N) e = N;
    int s = 0;
    for (int i = b; i < e; ++i) s += ind[i];
    sums[t] = s;
    __syncthreads();
    for (int off = 1; off < 1024; off <<= 1) {
        int v = (t >= off) ? sums[t - off] : 0;
        __syncthreads();
        sums[t] += v;
        __syncthreads();
    }
    int run = (t == 0) ? 0 : sums[t - 1];
    for (int i = b; i < e; ++i) {
        rowp[i] = run;
        cursor[i] = run;
        run += ind[i];
    }
    if (t == 1023) rowp[N] = sums[1023];
}

__global__ __launch_bounds__(256) void k_csrfill(
    const int* __restrict__ src, const int* __restrict__ dst, int E,
    int* __restrict__ cursor, int* __restrict__ csr)
{
    int i = blockIdx.x * 256 + threadIdx.x;
    if (i < E) {
        int pos = atomicAdd(&cursor[dst[i]], 1);
        csr[pos] = src[i];
    }
}

// WF[k][j] = sum_m proj_W[k][m] * W1[64+m][j]   (512x128)
__global__ __launch_bounds__(256) void k_wf(
    const float* __restrict__ projW, const float* __restrict__ W1,
    float* __restrict__ WF)
{
    int idx = blockIdx.x * 256 + threadIdx.x;
    int k = idx >> 7, j = idx & 127;
    const float* a = projW + (size_t)k * 128;
    float s = 0.f;
#pragma unroll 8
    for (int m = 0; m < 128; ++m) s = fmaf(a[m], W1[(size_t)(64 + m) * 128 + j], s);
    WF[idx] = s;
}

// cb[j] = sum_m proj_b[m] * W1[64+m][j]
__global__ void k_cb(const float* __restrict__ projb, const float* __restrict__ W1,
                     float* __restrict__ cb)
{
    int j = threadIdx.x;
    float s = 0.f;
    for (int m = 0; m < 128; ++m) s = fmaf(projb[m], W1[(size_t)(64 + m) * 128 + j], s);
    cb[j] = s;
}

// ---- k_h1 helpers: 40 virtual k-tiles over 3 A/B sources ----
__device__ __forceinline__ const float* h1_a_src(
    int t, int node, int didxn,
    const float* features, const float* logits, const float* deg_table)
{
    if (t < 32) return features + (size_t)node * 512 + t * 16;
    if (t < 36) return logits + (size_t)node * 64 + (t - 32) * 16;
    return deg_table + (size_t)didxn * 64 + (t - 36) * 16;
}

__device__ __forceinline__ const float* h1_b_src(
    int t, const float* WF, const float* W1)
{
    if (t < 32) return WF + (size_t)t * 16 * 128;
    if (t < 36) return W1 + (size_t)(t - 32) * 16 * 128;
    return W1 + (size_t)(192 + (t - 36) * 16) * 128;
}

// BM=128, BN=128, BK=16, 256 threads, 8x8 microtile. A and B in LDS.
__global__ __launch_bounds__(256, 2) void k_h1(
    const float* __restrict__ logits, const float* __restrict__ features,
    const float* __restrict__ deg_table, const int* __restrict__ didx,
    const float* __restrict__ WF, const float* __restrict__ W1,
    const float* __restrict__ cb, const float* __restrict__ cs,
    unsigned short* __restrict__ h1, int N)
{
    constexpr int BK = 16, NT = 40;
    __shared__ float As[BK][132];
    __shared__ float Bs[BK][128];
    int tid = threadIdx.x;
    int i0 = blockIdx.x * 128;
    int trow = tid >> 4, tcol = tid & 15;
    int la_row = tid >> 2;
    int la_k4 = (tid & 3) * 4;
    int nodeA0 = i0 + la_row;       if (nodeA0 >= N) nodeA0 = N - 1;
    int nodeA1 = i0 + la_row + 64;  if (nodeA1 >= N) nodeA1 = N - 1;
    int didx0 = didx[nodeA0];
    int didx1 = didx[nodeA1];
    float* BsFlat = &Bs[0][0];

    float acc[8][8];
#pragma unroll
    for (int r = 0; r < 8; ++r)
#pragma unroll
        for (int c = 0; c < 8; ++c) acc[r][c] = 0.f;

    // prologue: stage tile 0
    {
        float4 ra0 = *(const float4*)(h1_a_src(0, nodeA0, didx0, features, logits, deg_table) + la_k4);
        float4 ra1 = *(const float4*)(h1_a_src(0, nodeA1, didx1, features, logits, deg_table) + la_k4);
        const float* b0 = h1_b_src(0, WF, W1);
        float4 t0 = *(const float4*)(b0 + tid * 4);
        float4 t1 = *(const float4*)(b0 + 1024 + tid * 4);
        *(float4*)(BsFlat + tid * 4) = t0;
        *(float4*)(BsFlat + 1024 + tid * 4) = t1;
        As[la_k4 + 0][la_row] = ra0.x;
        As[la_k4 + 1][la_row] = ra0.y;
        As[la_k4 + 2][la_row] = ra0.z;
        As[la_k4 + 3][la_row] = ra0.w;
        As[la_k4 + 0][la_row + 64] = ra1.x;
        As[la_k4 + 1][la_row + 64] = ra1.y;
        As[la_k4 + 2][la_row + 64] = ra1.z;
        As[la_k4 + 3][la_row + 64] = ra1.w;
    }

    float4 ra0, ra1, rb0, rb1;
    for (int t = 0; t < NT; ++t) {
        __syncthreads();
        if (t + 1 < NT) {
            ra0 = *(const float4*)(h1_a_src(t + 1, nodeA0, didx0, features, logits, deg_table) + la_k4);
            ra1 = *(const float4*)(h1_a_src(t + 1, nodeA1, didx1, features, logits, deg_table) + la_k4);
            const float* bn = h1_b_src(t + 1, WF, W1);
            rb0 = *(const float4*)(bn + tid * 4);
            rb1 = *(const float4*)(bn + 1024 + tid * 4);
        }
#pragma unroll
        for (int kk = 0; kk < BK; ++kk) {
            float4 av0 = *(const float4*)&As[kk][trow * 8];
            float4 av1 = *(const float4*)&As[kk][trow * 8 + 4];
            float4 bv0 = *(const float4*)&Bs[kk][tcol * 8];
            float4 bv1 = *(const float4*)&Bs[kk][tcol * 8 + 4];
            float a_[8] = {av0.x, av0.y, av0.z, av0.w, av1.x, av1.y, av1.z, av1.w};
            float b_[8] = {bv0.x, bv0.y, bv0.z, bv0.w, bv1.x, bv1.y, bv1.z, bv1.w};
#pragma unroll
            for (int r = 0; r < 8; ++r)
#pragma unroll
                for (int c = 0; c < 8; ++c)
                    acc[r][c] = fmaf(a_[r], b_[c], acc[r][c]);
        }
        __syncthreads();
        if (t + 1 < NT) {
            As[la_k4 + 0][la_row] = ra0.x;
            As[la_k4 + 1][la_row] = ra0.y;
            As[la_k4 + 2][la_row] = ra0.z;
            As[la_k4 + 3][la_row] = ra0.w;
            As[la_k4 + 0][la_row + 64] = ra1.x;
            As[la_k4 + 1][la_row + 64] = ra1.y;
            As[la_k4 + 2][la_row + 64] = ra1.z;
            As[la_k4 + 3][la_row + 64] = ra1.w;
            *(float4*)(BsFlat + tid * 4) = rb0;
            *(float4*)(BsFlat + 1024 + tid * 4) = rb1;
        }
    }

    int col0 = tcol * 8;
    float4 cbv0 = *(const float4*)(cb + col0);
    float4 cbv1 = *(const float4*)(cb + col0 + 4);
#pragma unroll
    for (int r = 0; r < 8; ++r) {
        int node = i0 + trow * 8 + r;
        if (node < N) {
            float sc = cs[node];
            uint4 o;
            o.x = (unsigned)f2bf(sc * (acc[r][0] + cbv0.x)) |
                  ((unsigned)f2bf(sc * (acc[r][1] + cbv0.y)) << 16);
            o.y = (unsigned)f2bf(sc * (acc[r][2] + cbv0.z)) |
                  ((unsigned)f2bf(sc * (acc[r][3] + cbv0.w)) << 16);
            o.z = (unsigned)f2bf(sc * (acc[r][4] + cbv1.x)) |
                  ((unsigned)f2bf(sc * (acc[r][5] + cbv1.y)) << 16);
            o.w = (unsigned)f2bf(sc * (acc[r][6] + cbv1.z)) |
                  ((unsigned)f2bf(sc * (acc[r][7] + cbv1.w)) << 16);
            *(uint4*)(h1 + (size_t)node * 128 + col0) = o;
        }
    }
}

// Layer-1 aggregation: y[i] = relu( (sum_{e: dst=i} h1[src_e]) * cd[i] + b1 )
// h1 is bf16; each lane handles 2 columns (one dword gather per edge).
__global__ __launch_bounds__(256) void k_agg1(
    const unsigned short* __restrict__ h1, const int* __restrict__ rowp,
    const int* __restrict__ csr, const float* __restrict__ cd,
    const float* __restrict__ b1, float* __restrict__ y, int N)
{
    int i = blockIdx.x * 4 + (threadIdx.x >> 6);
    if (i >= N) return;
    int lane = threadIdx.x & 63;
    int s0 = rowp[i], s1 = rowp[i + 1];
    float ax = 0.f, ay = 0.f;
    int e = s0;
    for (; e + 4 <= s1; e += 4) {
        int j0 = csr[e], j1 = csr[e + 1], j2 = csr[e + 2], j3 = csr[e + 3];
        unsigned u0 = *(const unsigned*)(h1 + (size_t)j0 * 128 + lane * 2);
        unsigned u1 = *(const unsigned*)(h1 + (size_t)j1 * 128 + lane * 2);
        unsigned u2 = *(const unsigned*)(h1 + (size_t)j2 * 128 + lane * 2);
        unsigned u3 = *(const unsigned*)(h1 + (size_t)j3 * 128 + lane * 2);
        ax += (__uint_as_float(u0 << 16) + __uint_as_float(u1 << 16)) +
              (__uint_as_float(u2 << 16) + __uint_as_float(u3 << 16));
        ay += (__uint_as_float(u0 & 0xffff0000u) + __uint_as_float(u1 & 0xffff0000u)) +
              (__uint_as_float(u2 & 0xffff0000u) + __uint_as_float(u3 & 0xffff0000u));
    }
    for (; e < s1; ++e) {
        unsigned u = *(const unsigned*)(h1 + (size_t)csr[e] * 128 + lane * 2);
        ax += __uint_as_float(u << 16);
        ay += __uint_as_float(u & 0xffff0000u);
    }
    float cdi = cd[i];
    float2 o;
    o.x = fmaxf(fmaf(ax, cdi, b1[lane * 2 + 0]), 0.f);
    o.y = fmaxf(fmaf(ay, cdi, b1[lane * 2 + 1]), 0.f);
    *(float2*)(y + (size_t)i * 128 + lane * 2) = o;
}

// h2 = cs * (y @ W2)   M=100K, N=64, K=128; A and B in LDS; h2 out bf16.
__global__ __launch_bounds__(256, 2) void k_h2(
    const float* __restrict__ y, const float* __restrict__ W2,
    const float* __restrict__ cs, unsigned short* __restrict__ h2, int N)
{
    constexpr int BK = 16, NT = 8;
    __shared__ float As[BK][132];
    __shared__ float Bs[BK][64];
    int tid = threadIdx.x;
    int i0 = blockIdx.x * 128;
    int trow = tid >> 4, tcol = tid & 15;
    int la_row = tid >> 2;
    int la_k4 = (tid & 3) * 4;
    int n0 = i0 + la_row;      if (n0 >= N) n0 = N - 1;
    int n1 = i0 + la_row + 64; if (n1 >= N) n1 = N - 1;
    const float* a0 = y + (size_t)n0 * 128 + la_k4;
    const float* a1 = y + (size_t)n1 * 128 + la_k4;
    float* BsFlat = &Bs[0][0];

    float acc[8][4];
#pragma unroll
    for (int r = 0; r < 8; ++r)
#pragma unroll
        for (int c = 0; c < 4; ++c) acc[r][c] = 0.f;

    {
        float4 ra0 = *(const float4*)(a0);
        float4 ra1 = *(const float4*)(a1);
        float4 t0 = *(const float4*)(W2 + tid * 4);
        *(float4*)(BsFlat + tid * 4) = t0;
        As[la_k4 + 0][la_row] = ra0.x;
        As[la_k4 + 1][la_row] = ra0.y;
        As[la_k4 + 2][la_row] = ra0.z;
        As[la_k4 + 3][la_row] = ra0.w;
        As[la_k4 + 0][la_row + 64] = ra1.x;
        As[la_k4 + 1][la_row + 64] = ra1.y;
        As[la_k4 + 2][la_row + 64] = ra1.z;
        As[la_k4 + 3][la_row + 64] = ra1.w;
    }

    float4 ra0, ra1, rb0;
    for (int t = 0; t < NT; ++t) {
        __syncthreads();
        if (t + 1 < NT) {
            ra0 = *(const float4*)(a0 + (t + 1) * BK);
            ra1 = *(const float4*)(a1 + (t + 1) * BK);
            rb0 = *(const float4*)(W2 + (size_t)(t + 1) * BK * 64 + tid * 4);
        }
#pragma unroll
        for (int kk = 0; kk < BK; ++kk) {
            float4 av0 = *(const float4*)&As[kk][trow * 8];
            float4 av1 = *(const float4*)&As[kk][trow * 8 + 4];
            float4 bv = *(const float4*)&Bs[kk][tcol * 4];
            float a_[8] = {av0.x, av0.y, av0.z, av0.w, av1.x, av1.y, av1.z, av1.w};
            float b_[4] = {bv.x, bv.y, bv.z, bv.w};
#pragma unroll
            for (int r = 0; r < 8; ++r)
#pragma unroll
                for (int c = 0; c < 4; ++c)
                    acc[r][c] = fmaf(a_[r], b_[c], acc[r][c]);
        }
        __syncthreads();
        if (t + 1 < NT) {
            As[la_k4 + 0][la_row] = ra0.x;
            As[la_k4 + 1][la_row] = ra0.y;
            As[la_k4 + 2][la_row] = ra0.z;
            As[la_k4 + 3][la_row] = ra0.w;
            As[la_k4 + 0][la_row + 64] = ra1.x;
            As[la_k4 + 1][la_row + 64] = ra1.y;
            As[la_k4 + 2][la_row + 64] = ra1.z;
            As[la_k4 + 3][la_row + 64] = ra1.w;
            *(float4*)(BsFlat + tid * 4) = rb0;
        }
    }

#pragma unroll
    for (int r = 0; r < 8; ++r) {
        int node = i0 + trow * 8 + r;
        if (node < N) {
            float sc = cs[node];
            uint2 o;
            o.x = (unsigned)f2bf(sc * acc[r][0]) | ((unsigned)f2bf(sc * acc[r][1]) << 16);
            o.y = (unsigned)f2bf(sc * acc[r][2]) | ((unsigned)f2bf(sc * acc[r][3]) << 16);
            *(uint2*)(h2 + (size_t)node * 64 + tcol * 4) = o;
        }
    }
}

// Layer-2 aggregation: out[i] = (sum h2[src_e]) * cd[i] + b2 ; h2 is bf16.
__global__ __launch_bounds__(256) void k_agg2(
    const unsigned short* __restrict__ h2, const int* __restrict__ rowp,
    const int* __restrict__ csr, const float* __restrict__ cd,
    const float* __restrict__ b2, float* __restrict__ out, int N)
{
    int i = blockIdx.x * 4 + (threadIdx.x >> 6);
    if (i >= N) return;
    int lane = threadIdx.x & 63;
    int s0 = rowp[i], s1 = rowp[i + 1];
    float a = 0.f;
    int e = s0;
    for (; e + 4 <= s1; e += 4) {
        int j0 = csr[e], j1 = csr[e + 1], j2 = csr[e + 2], j3 = csr[e + 3];
        float v0 = bf2f(h2[(size_t)j0 * 64 + lane]);
        float v1 = bf2f(h2[(size_t)j1 * 64 + lane]);
        float v2 = bf2f(h2[(size_t)j2 * 64 + lane]);
        float v3 = bf2f(h2[(size_t)j3 * 64 + lane]);
        a += (v0 + v1) + (v2 + v3);
    }
    for (; e < s1; ++e) a += bf2f(h2[(size_t)csr[e] * 64 + lane]);
    out[(size_t)i * 64 + lane] = fmaf(a, cd[i], b2[lane]);
}

extern "C" void kernel_launch(void* const* d_in, const int* in_sizes, int n_in,
                              void* d_out, int out_size, void* d_ws, size_t ws_size,
                              hipStream_t stream)
{
    const int* src = (const int*)d_in[0];
    const int* dst = (const int*)d_in[1];
    const float* logits = (const float*)d_in[2];
    const float* features = (const float*)d_in[3];
    const float* projW = (const float*)d_in[4];
    const float* projb = (const float*)d_in[5];
    const float* deg_table = (const float*)d_in[6];
    const float* W1 = (const float*)d_in[7];
    const float* b1 = (const float*)d_in[8];
    const float* W2 = (const float*)d_in[9];
    const float* b2 = (const float*)d_in[10];
    const int E = in_sizes[0];
    const int N = in_sizes[2] / 64;

    char* base = (char*)d_ws;
    size_t off = 0;
    auto alloc = [&](size_t bytes) -> void* {
        void* p = base + off;
        off += (bytes + 255) & ~(size_t)255;
        return p;
    };
    int* outd   = (int*)alloc((size_t)N * 4);
    int* ind    = (int*)alloc((size_t)N * 4);
    int* rowp   = (int*)alloc((size_t)(N + 1) * 4);
    int* cursor = (int*)alloc((size_t)N * 4);
    int* csr    = (int*)alloc((size_t)E * 4);
    int* didx   = (int*)alloc((size_t)N * 4);
    float* cs   = (float*)alloc((size_t)N * 4);
    float* cd   = (float*)alloc((size_t)N * 4);
    float* WF   = (float*)alloc((size_t)512 * 128 * 4);
    float* cb   = (float*)alloc((size_t)128 * 4);
    unsigned short* h1 = (unsigned short*)alloc((size_t)N * 128 * 2);
    float* yb   = (float*)alloc((size_t)N * 128 * 4);
    unsigned short* h2 = h1;   // h1 dead after k_agg1; reuse (needs N*64*2)
    float* outp = (float*)d_out;

    hipMemsetAsync(outd, 0, (size_t)N * 4, stream);
    hipMemsetAsync(ind, 0, (size_t)N * 4, stream);

    int eb = (E + 255) / 256;
    int nb = (N + 255) / 256;
    int mb = (N + 127) / 128;

    k_degrees<<<eb, 256, 0, stream>>>(src, dst, E, outd, ind);
    k_norms<<<nb, 256, 0, stream>>>(outd, ind, N, cs, cd, didx);
    k_scan<<<1, 1024, 0, stream>>>(ind, N, rowp, cursor);
    k_csrfill<<<eb, 256, 0, stream>>>(src, dst, E, cursor, csr);
    k_wf<<<256, 256, 0, stream>>>(projW, W1, WF);
    k_cb<<<1, 128, 0, stream>>>(projb, W1, cb);
    k_h1<<<mb, 256, 0, stream>>>(logits, features, deg_table, didx, WF, W1, cb, cs, h1, N);
    k_agg1<<<(N + 3) / 4, 256, 0, stream>>>(h1, rowp, csr, cd, b1, yb, N);
    k_h2<<<mb, 256, 0, stream>>>(yb, W2, cs, h2, N);
    k_agg2<<<(N + 3) / 4, 256, 0, stream>>>(h2, rowp, csr, cd, b2, outp, N);
}

// Round 5
// 741.538 us; speedup vs baseline: 2.1751x; 1.3221x over previous
//
#include <hip/hip_runtime.h>
#include <cstdint>
#include <cstddef>

// ---------------------------------------------------------------------------
// GCN forward, MFMA edition:
//   deg -> cs/cd/didx -> CSR(dst) -> WF=projW@W1mid -> WT=[col][k] hi/lo bf16
//   -> h1 = cs*(x@W1+cb)  [split-bf16 3-term MFMA, fp32-class accuracy]
//   -> agg1 -> y = relu(agg1*cd+b1) -> h2 = cs*(y@W2) [MFMA] -> agg2 -> out
// Split trick: a = a_hi + a_lo (both bf16; a_lo = bf16(a - a_hi) captures the
// residual, so hi may be truncated). D = ahi*bhi + alo*bhi + ahi*blo leaves
// only O(2^-17)-relative terms -> output error unchanged vs fp32 path.
// R4 lessons: 128-VGPR cap spilled acc (WRITE 103MB for 26MB output) -> stay
// at (256,2); stride-8 LDS reads 4-way conflict (18M) -> all LDS tiles use
// 40-elem (80B = 20-bank) row stride: 2-way max = free per m136.
// ---------------------------------------------------------------------------

typedef short short8 __attribute__((ext_vector_type(8)));
typedef float f32x4 __attribute__((ext_vector_type(4)));

__device__ __forceinline__ unsigned short f2bf(float f) {
    unsigned u = __float_as_uint(f);
    u += 0x7fff + ((u >> 16) & 1);   // RNE
    return (unsigned short)(u >> 16);
}
__device__ __forceinline__ float bf2f(unsigned short s) {
    return __uint_as_float(((unsigned)s) << 16);
}

// 8 fp32 -> hi bf16 (trunc) + lo bf16 (trunc of residual)
__device__ __forceinline__ void split_f4(float4 a, float4 b, short8& hv, short8& lv) {
    float f[8] = {a.x, a.y, a.z, a.w, b.x, b.y, b.z, b.w};
#pragma unroll
    for (int i = 0; i < 8; ++i) {
        unsigned u = __float_as_uint(f[i]);
        hv[i] = (short)(u >> 16);
        float r = f[i] - __uint_as_float(u & 0xffff0000u);
        lv[i] = (short)(__float_as_uint(r) >> 16);
    }
}

__global__ __launch_bounds__(256) void k_degrees(
    const int* __restrict__ src, const int* __restrict__ dst, int E,
    int* __restrict__ outd, int* __restrict__ ind)
{
    int i = blockIdx.x * 256 + threadIdx.x;
    if (i < E) {
        atomicAdd(&outd[src[i]], 1);
        atomicAdd(&ind[dst[i]], 1);
    }
}

__global__ __launch_bounds__(256) void k_norms(
    const int* __restrict__ outd, const int* __restrict__ ind, int N,
    float* __restrict__ cs, float* __restrict__ cd, int* __restrict__ didx)
{
    int i = blockIdx.x * 256 + threadIdx.x;
    if (i < N) {
        int od = outd[i], id = ind[i];
        cs[i] = rsqrtf((float)(od > 0 ? od : 1));
        cd[i] = rsqrtf((float)(id > 0 ? id : 1));
        int d = od + id;
        didx[i] = d > 511 ? 511 : d;
    }
}

__global__ __launch_bounds__(1024) void k_scan(
    const int* __restrict__ ind, int N,
    int* __restrict__ rowp, int* __restrict__ cursor)
{
    __shared__ int sums[1024];
    int t = threadIdx.x;
    int chunk = (N + 1023) >> 10;
    int b = t * chunk, e = b + chunk;
    if (b > N) b = N;
    if (e > N) e = N;
    int s = 0;
    for (int i = b; i < e; ++i) s += ind[i];
    sums[t] = s;
    __syncthreads();
    for (int off = 1; off < 1024; off <<= 1) {
        int v = (t >= off) ? sums[t - off] : 0;
        __syncthreads();
        sums[t] += v;
        __syncthreads();
    }
    int run = (t == 0) ? 0 : sums[t - 1];
    for (int i = b; i < e; ++i) {
        rowp[i] = run;
        cursor[i] = run;
        run += ind[i];
    }
    if (t == 1023) rowp[N] = sums[1023];
}

__global__ __launch_bounds__(256) void k_csrfill(
    const int* __restrict__ src, const int* __restrict__ dst, int E,
    int* __restrict__ cursor, int* __restrict__ csr)
{
    int i = blockIdx.x * 256 + threadIdx.x;
    if (i < E) {
        int pos = atomicAdd(&cursor[dst[i]], 1);
        csr[pos] = src[i];
    }
}

// WF[k][j] = sum_m projW[k][m] * W1[64+m][j]   (512x128 fp32)
__global__ __launch_bounds__(256) void k_wf(
    const float* __restrict__ projW, const float* __restrict__ W1,
    float* __restrict__ WF)
{
    int idx = blockIdx.x * 256 + threadIdx.x;
    int k = idx >> 7, j = idx & 127;
    const float* a = projW + (size_t)k * 128;
    float s = 0.f;
#pragma unroll 8
    for (int m = 0; m < 128; ++m) s = fmaf(a[m], W1[(size_t)(64 + m) * 128 + j], s);
    WF[idx] = s;
}

__global__ void k_cb(const float* __restrict__ projb, const float* __restrict__ W1,
                     float* __restrict__ cb)
{
    int j = threadIdx.x;
    float s = 0.f;
    for (int m = 0; m < 128; ++m) s = fmaf(projb[m], W1[(size_t)(64 + m) * 128 + j], s);
    cb[j] = s;
}

// WT[j][k], j=0..127, k=0..639: virtual-K weight matrix, transposed, split
// into bf16 hi/lo. k<512: WF; k<576: W1 rows 0..63 (logits); else W1 rows
// 192..255 (deg emb).
__global__ __launch_bounds__(256) void k_wt1(
    const float* __restrict__ WF, const float* __restrict__ W1,
    unsigned short* __restrict__ wt_hi, unsigned short* __restrict__ wt_lo)
{
    int idx = blockIdx.x * 256 + threadIdx.x;   // 128*640
    int j = idx / 640, k = idx - j * 640;
    float v;
    if (k < 512) v = WF[(size_t)k * 128 + j];
    else if (k < 576) v = W1[(size_t)(k - 512) * 128 + j];
    else v = W1[(size_t)(192 + k - 576) * 128 + j];
    unsigned short h = f2bf(v);
    wt_hi[idx] = h;
    float r = v - bf2f(h);
    wt_lo[idx] = (unsigned short)(__float_as_uint(r) >> 16);
}

// W2T[j][k], j=0..63, k=0..127
__global__ __launch_bounds__(256) void k_wt2(
    const float* __restrict__ W2,
    unsigned short* __restrict__ w2t_hi, unsigned short* __restrict__ w2t_lo)
{
    int idx = blockIdx.x * 256 + threadIdx.x;   // 64*128
    int j = idx >> 7, k = idx & 127;
    float v = W2[(size_t)k * 64 + j];
    unsigned short h = f2bf(v);
    w2t_hi[idx] = h;
    float r = v - bf2f(h);
    w2t_lo[idx] = (unsigned short)(__float_as_uint(r) >> 16);
}

// ---- k_h1: 128x128 tile, 4 waves (2x2), wave=64x64 (4x4 frags of 16x16),
//      K = 20 steps x 32, split-bf16 3-term MFMA. LDS row stride 40 elems.
__global__ __launch_bounds__(256, 2) void k_h1(
    const float* __restrict__ logits, const float* __restrict__ features,
    const float* __restrict__ deg_table, const int* __restrict__ didx,
    const unsigned short* __restrict__ wt_hi, const unsigned short* __restrict__ wt_lo,
    const float* __restrict__ cb, const float* __restrict__ cs,
    unsigned short* __restrict__ h1, int N)
{
    constexpr int NT = 20;
    __shared__ short Ah[128 * 40], Al[128 * 40], Bh[128 * 40], Bl[128 * 40];
    int tid = threadIdx.x;
    int i0 = blockIdx.x * 128;
    // staging: A: thread -> (row sr, k-half sh); B: thread -> (col sc, chunk pair sq)
    int sr = tid >> 1, sh = tid & 1;
    int snode = i0 + sr; if (snode >= N) snode = N - 1;
    int sdidx = didx[snode];
    int sc = tid >> 1, sq = (tid & 1) * 2;
    // compute: wave (wr,wc), frag row fr, k-group kg
    int lane = tid & 63, w = tid >> 6;
    int wr = w >> 1, wc = w & 1;
    int fr = lane & 15, kg = lane >> 4;
    int aoff = (wr * 64 + fr) * 40 + kg * 8;
    int boff = (wc * 64 + fr) * 40 + kg * 8;

    f32x4 acc[4][4];
#pragma unroll
    for (int ri = 0; ri < 4; ++ri)
#pragma unroll
        for (int ci = 0; ci < 4; ++ci) acc[ri][ci] = (f32x4)0.f;

    float4 fa0, fa1, fa2, fa3;
    uint4 pbh0, pbh1, pbl0, pbl1;

    auto loadT = [&](int t) {
        const float* ap;
        if (t < 16)      ap = features  + (size_t)snode * 512 + t * 32 + sh * 16;
        else if (t < 18) ap = logits    + (size_t)snode * 64 + (t - 16) * 32 + sh * 16;
        else             ap = deg_table + (size_t)sdidx * 64 + (t - 18) * 32 + sh * 16;
        fa0 = *(const float4*)(ap);
        fa1 = *(const float4*)(ap + 4);
        fa2 = *(const float4*)(ap + 8);
        fa3 = *(const float4*)(ap + 12);
        const unsigned short* bh = wt_hi + (size_t)sc * 640 + t * 32 + sq * 8;
        const unsigned short* bl = wt_lo + (size_t)sc * 640 + t * 32 + sq * 8;
        pbh0 = *(const uint4*)(bh);
        pbh1 = *(const uint4*)(bh + 8);
        pbl0 = *(const uint4*)(bl);
        pbl1 = *(const uint4*)(bl + 8);
    };
    auto writeT = [&]() {
        short8 h0, l0, h1v, l1v;
        split_f4(fa0, fa1, h0, l0);
        split_f4(fa2, fa3, h1v, l1v);
        int ao = sr * 40 + sh * 16;
        *(short8*)&Ah[ao] = h0;      *(short8*)&Ah[ao + 8] = h1v;
        *(short8*)&Al[ao] = l0;      *(short8*)&Al[ao + 8] = l1v;
        int bo = sc * 40 + sq * 8;
        *(uint4*)&Bh[bo] = pbh0;     *(uint4*)&Bh[bo + 8] = pbh1;
        *(uint4*)&Bl[bo] = pbl0;     *(uint4*)&Bl[bo + 8] = pbl1;
    };

    loadT(0);
    writeT();
    for (int t = 0; t < NT; ++t) {
        __syncthreads();
        if (t + 1 < NT) loadT(t + 1);
        short8 ah[4], al[4];
#pragma unroll
        for (int ri = 0; ri < 4; ++ri) {
            ah[ri] = *(const short8*)&Ah[aoff + ri * 640];
            al[ri] = *(const short8*)&Al[aoff + ri * 640];
        }
#pragma unroll
        for (int ci = 0; ci < 4; ++ci) {
            short8 bh = *(const short8*)&Bh[boff + ci * 640];
            short8 bl = *(const short8*)&Bl[boff + ci * 640];
#pragma unroll
            for (int ri = 0; ri < 4; ++ri) {
                acc[ri][ci] = __builtin_amdgcn_mfma_f32_16x16x32_bf16(ah[ri], bh, acc[ri][ci], 0, 0, 0);
                acc[ri][ci] = __builtin_amdgcn_mfma_f32_16x16x32_bf16(al[ri], bh, acc[ri][ci], 0, 0, 0);
                acc[ri][ci] = __builtin_amdgcn_mfma_f32_16x16x32_bf16(ah[ri], bl, acc[ri][ci], 0, 0, 0);
            }
        }
        __syncthreads();
        if (t + 1 < NT) writeT();
    }

    // epilogue: C/D layout col = lane&15, row = (lane>>4)*4 + reg  [m89]
    float cbv[4];
#pragma unroll
    for (int ci = 0; ci < 4; ++ci) cbv[ci] = cb[wc * 64 + ci * 16 + fr];
#pragma unroll
    for (int ri = 0; ri < 4; ++ri) {
#pragma unroll
        for (int j = 0; j < 4; ++j) {
            int row = i0 + wr * 64 + ri * 16 + kg * 4 + j;
            if (row < N) {
                float scv = cs[row];
#pragma unroll
                for (int ci = 0; ci < 4; ++ci) {
                    int col = wc * 64 + ci * 16 + fr;
                    h1[(size_t)row * 128 + col] = f2bf(scv * (acc[ri][ci][j] + cbv[ci]));
                }
            }
        }
    }
}

// Layer-1 aggregation: y[i] = relu( (sum_{e: dst=i} h1[src_e]) * cd[i] + b1 )
__global__ __launch_bounds__(256) void k_agg1(
    const unsigned short* __restrict__ h1, const int* __restrict__ rowp,
    const int* __restrict__ csr, const float* __restrict__ cd,
    const float* __restrict__ b1, float* __restrict__ y, int N)
{
    int i = blockIdx.x * 4 + (threadIdx.x >> 6);
    if (i >= N) return;
    int lane = threadIdx.x & 63;
    int s0 = rowp[i], s1 = rowp[i + 1];
    float ax = 0.f, ay = 0.f;
    int e = s0;
    for (; e + 4 <= s1; e += 4) {
        int j0 = csr[e], j1 = csr[e + 1], j2 = csr[e + 2], j3 = csr[e + 3];
        unsigned u0 = *(const unsigned*)(h1 + (size_t)j0 * 128 + lane * 2);
        unsigned u1 = *(const unsigned*)(h1 + (size_t)j1 * 128 + lane * 2);
        unsigned u2 = *(const unsigned*)(h1 + (size_t)j2 * 128 + lane * 2);
        unsigned u3 = *(const unsigned*)(h1 + (size_t)j3 * 128 + lane * 2);
        ax += (__uint_as_float(u0 << 16) + __uint_as_float(u1 << 16)) +
              (__uint_as_float(u2 << 16) + __uint_as_float(u3 << 16));
        ay += (__uint_as_float(u0 & 0xffff0000u) + __uint_as_float(u1 & 0xffff0000u)) +
              (__uint_as_float(u2 & 0xffff0000u) + __uint_as_float(u3 & 0xffff0000u));
    }
    for (; e < s1; ++e) {
        unsigned u = *(const unsigned*)(h1 + (size_t)csr[e] * 128 + lane * 2);
        ax += __uint_as_float(u << 16);
        ay += __uint_as_float(u & 0xffff0000u);
    }
    float cdi = cd[i];
    float2 o;
    o.x = fmaxf(fmaf(ax, cdi, b1[lane * 2 + 0]), 0.f);
    o.y = fmaxf(fmaf(ay, cdi, b1[lane * 2 + 1]), 0.f);
    *(float2*)(y + (size_t)i * 128 + lane * 2) = o;
}

// ---- k_h2: h2 = cs*(y@W2), 128x64 tile, wave=64x32 (4x2 frags), K=4x32.
__global__ __launch_bounds__(256, 2) void k_h2(
    const float* __restrict__ y,
    const unsigned short* __restrict__ w2t_hi, const unsigned short* __restrict__ w2t_lo,
    const float* __restrict__ cs, unsigned short* __restrict__ h2, int N)
{
    constexpr int NT = 4;
    __shared__ short Ah[128 * 40], Al[128 * 40], Bh[64 * 40], Bl[64 * 40];
    int tid = threadIdx.x;
    int i0 = blockIdx.x * 128;
    int sr = tid >> 1, sh = tid & 1;
    int snode = i0 + sr; if (snode >= N) snode = N - 1;
    const float* abase = y + (size_t)snode * 128 + sh * 16;
    int sc = tid >> 2, sq = tid & 3;
    int lane = tid & 63, w = tid >> 6;
    int wr = w >> 1, wc = w & 1;
    int fr = lane & 15, kg = lane >> 4;
    int aoff = (wr * 64 + fr) * 40 + kg * 8;
    int boff = (wc * 32 + fr) * 40 + kg * 8;

    f32x4 acc[4][2];
#pragma unroll
    for (int ri = 0; ri < 4; ++ri)
#pragma unroll
        for (int ci = 0; ci < 2; ++ci) acc[ri][ci] = (f32x4)0.f;

    float4 fa0, fa1, fa2, fa3;
    uint4 pbh0, pbl0;

    auto loadT = [&](int t) {
        const float* ap = abase + t * 32;
        fa0 = *(const float4*)(ap);
        fa1 = *(const float4*)(ap + 4);
        fa2 = *(const float4*)(ap + 8);
        fa3 = *(const float4*)(ap + 12);
        pbh0 = *(const uint4*)(w2t_hi + (size_t)sc * 128 + t * 32 + sq * 8);
        pbl0 = *(const uint4*)(w2t_lo + (size_t)sc * 128 + t * 32 + sq * 8);
    };
    auto writeT = [&]() {
        short8 h0, l0, h1v, l1v;
        split_f4(fa0, fa1, h0, l0);
        split_f4(fa2, fa3, h1v, l1v);
        int ao = sr * 40 + sh * 16;
        *(short8*)&Ah[ao] = h0;      *(short8*)&Ah[ao + 8] = h1v;
        *(short8*)&Al[ao] = l0;      *(short8*)&Al[ao + 8] = l1v;
        int bo = sc * 40 + sq * 8;
        *(uint4*)&Bh[bo] = pbh0;
        *(uint4*)&Bl[bo] = pbl0;
    };

    loadT(0);
    writeT();
    for (int t = 0; t < NT; ++t) {
        __syncthreads();
        if (t + 1 < NT) loadT(t + 1);
        short8 ah[4], al[4];
#pragma unroll
        for (int ri = 0; ri < 4; ++ri) {
            ah[ri] = *(const short8*)&Ah[aoff + ri * 640];
            al[ri] = *(const short8*)&Al[aoff + ri * 640];
        }
#pragma unroll
        for (int ci = 0; ci < 2; ++ci) {
            short8 bh = *(const short8*)&Bh[boff + ci * 640];
            short8 bl = *(const short8*)&Bl[boff + ci * 640];
#pragma unroll
            for (int ri = 0; ri < 4; ++ri) {
                acc[ri][ci] = __builtin_amdgcn_mfma_f32_16x16x32_bf16(ah[ri], bh, acc[ri][ci], 0, 0, 0);
                acc[ri][ci] = __builtin_amdgcn_mfma_f32_16x16x32_bf16(al[ri], bh, acc[ri][ci], 0, 0, 0);
                acc[ri][ci] = __builtin_amdgcn_mfma_f32_16x16x32_bf16(ah[ri], bl, acc[ri][ci], 0, 0, 0);
            }
        }
        __syncthreads();
        if (t + 1 < NT) writeT();
    }

#pragma unroll
    for (int ri = 0; ri < 4; ++ri) {
#pragma unroll
        for (int j = 0; j < 4; ++j) {
            int row = i0 + wr * 64 + ri * 16 + kg * 4 + j;
            if (row < N) {
                float scv = cs[row];
#pragma unroll
                for (int ci = 0; ci < 2; ++ci) {
                    int col = wc * 32 + ci * 16 + fr;
                    h2[(size_t)row * 64 + col] = f2bf(scv * acc[ri][ci][j]);
                }
            }
        }
    }
}

// Layer-2 aggregation: out[i] = (sum h2[src_e]) * cd[i] + b2
__global__ __launch_bounds__(256) void k_agg2(
    const unsigned short* __restrict__ h2, const int* __restrict__ rowp,
    const int* __restrict__ csr, const float* __restrict__ cd,
    const float* __restrict__ b2, float* __restrict__ out, int N)
{
    int i = blockIdx.x * 4 + (threadIdx.x >> 6);
    if (i >= N) return;
    int lane = threadIdx.x & 63;
    int s0 = rowp[i], s1 = rowp[i + 1];
    float a = 0.f;
    int e = s0;
    for (; e + 4 <= s1; e += 4) {
        int j0 = csr[e], j1 = csr[e + 1], j2 = csr[e + 2], j3 = csr[e + 3];
        float v0 = bf2f(h2[(size_t)j0 * 64 + lane]);
        float v1 = bf2f(h2[(size_t)j1 * 64 + lane]);
        float v2 = bf2f(h2[(size_t)j2 * 64 + lane]);
        float v3 = bf2f(h2[(size_t)j3 * 64 + lane]);
        a += (v0 + v1) + (v2 + v3);
    }
    for (; e < s1; ++e) a += bf2f(h2[(size_t)csr[e] * 64 + lane]);
    out[(size_t)i * 64 + lane] = fmaf(a, cd[i], b2[lane]);
}

extern "C" void kernel_launch(void* const* d_in, const int* in_sizes, int n_in,
                              void* d_out, int out_size, void* d_ws, size_t ws_size,
                              hipStream_t stream)
{
    const int* src = (const int*)d_in[0];
    const int* dst = (const int*)d_in[1];
    const float* logits = (const float*)d_in[2];
    const float* features = (const float*)d_in[3];
    const float* projW = (const float*)d_in[4];
    const float* projb = (const float*)d_in[5];
    const float* deg_table = (const float*)d_in[6];
    const float* W1 = (const float*)d_in[7];
    const float* b1 = (const float*)d_in[8];
    const float* W2 = (const float*)d_in[9];
    const float* b2 = (const float*)d_in[10];
    const int E = in_sizes[0];
    const int N = in_sizes[2] / 64;

    char* base = (char*)d_ws;
    size_t off = 0;
    auto alloc = [&](size_t bytes) -> void* {
        void* p = base + off;
        off += (bytes + 255) & ~(size_t)255;
        return p;
    };
    int* outd   = (int*)alloc((size_t)N * 4);
    int* ind    = (int*)alloc((size_t)N * 4);
    int* rowp   = (int*)alloc((size_t)(N + 1) * 4);
    int* cursor = (int*)alloc((size_t)N * 4);
    int* csr    = (int*)alloc((size_t)E * 4);
    int* didx   = (int*)alloc((size_t)N * 4);
    float* cs   = (float*)alloc((size_t)N * 4);
    float* cd   = (float*)alloc((size_t)N * 4);
    float* WF   = (float*)alloc((size_t)512 * 128 * 4);
    float* cb   = (float*)alloc((size_t)128 * 4);
    unsigned short* wt_hi  = (unsigned short*)alloc((size_t)128 * 640 * 2);
    unsigned short* wt_lo  = (unsigned short*)alloc((size_t)128 * 640 * 2);
    unsigned short* w2t_hi = (unsigned short*)alloc((size_t)64 * 128 * 2);
    unsigned short* w2t_lo = (unsigned short*)alloc((size_t)64 * 128 * 2);
    unsigned short* h1 = (unsigned short*)alloc((size_t)N * 128 * 2);
    float* yb   = (float*)alloc((size_t)N * 128 * 4);
    unsigned short* h2 = h1;   // h1 dead after k_agg1; reuse (needs N*64*2)
    float* outp = (float*)d_out;

    hipMemsetAsync(outd, 0, (size_t)N * 4, stream);
    hipMemsetAsync(ind, 0, (size_t)N * 4, stream);

    int eb = (E + 255) / 256;
    int nb = (N + 255) / 256;
    int mb = (N + 127) / 128;

    k_degrees<<<eb, 256, 0, stream>>>(src, dst, E, outd, ind);
    k_norms<<<nb, 256, 0, stream>>>(outd, ind, N, cs, cd, didx);
    k_scan<<<1, 1024, 0, stream>>>(ind, N, rowp, cursor);
    k_csrfill<<<eb, 256, 0, stream>>>(src, dst, E, cursor, csr);
    k_wf<<<256, 256, 0, stream>>>(projW, W1, WF);
    k_cb<<<1, 128, 0, stream>>>(projb, W1, cb);
    k_wt1<<<320, 256, 0, stream>>>(WF, W1, wt_hi, wt_lo);
    k_wt2<<<32, 256, 0, stream>>>(W2, w2t_hi, w2t_lo);
    k_h1<<<mb, 256, 0, stream>>>(logits, features, deg_table, didx, wt_hi, wt_lo, cb, cs, h1, N);
    k_agg1<<<(N + 3) / 4, 256, 0, stream>>>(h1, rowp, csr, cd, b1, yb, N);
    k_h2<<<mb, 256, 0, stream>>>(yb, w2t_hi, w2t_lo, cs, h2, N);
    k_agg2<<<(N + 3) / 4, 256, 0, stream>>>(h2, rowp, csr, cd, b2, outp, N);
}

// Round 6
// 516.314 us; speedup vs baseline: 3.1239x; 1.4362x over previous
//
#include <hip/hip_runtime.h>
#include <cstdint>
#include <cstddef>

// ---------------------------------------------------------------------------
// GCN forward, MFMA edition:
//   deg -> cs/cd/didx -> CSR(dst) -> WF=projW@W1mid -> WT=[col][k] hi/lo bf16
//   -> h1 = cs*(x@W1+cb)  [split-bf16 3-term MFMA, fp32-class accuracy]
//   -> agg1 -> y = relu(agg1*cd+b1) -> h2 = cs*(y@W2) [MFMA] -> agg2 -> out
// Split trick: a = a_hi + a_lo (bf16 trunc + bf16 residual);
// D = ahi*bhi + alo*bhi + ahi*blo -> only O(2^-17) rel. terms dropped.
// R5 lesson: single-block scan = 228 us on one CU -> 3-phase multi-block
// scan (~15 us). agg kernels are gather-LATENCY-bound (bf16 bought little):
// agg2 now 32-lane/node dword gathers; both aggs unroll 8 for MLP.
// R4 lessons: don't cap VGPRs below acc needs (spill -> 103MB writes);
// LDS row stride 40 elems (20 banks) keeps MFMA frag reads 2-way max = free.
// ---------------------------------------------------------------------------

typedef short short8 __attribute__((ext_vector_type(8)));
typedef float f32x4 __attribute__((ext_vector_type(4)));

__device__ __forceinline__ unsigned short f2bf(float f) {
    unsigned u = __float_as_uint(f);
    u += 0x7fff + ((u >> 16) & 1);   // RNE
    return (unsigned short)(u >> 16);
}
__device__ __forceinline__ float bf2f(unsigned short s) {
    return __uint_as_float(((unsigned)s) << 16);
}

__device__ __forceinline__ void split_f4(float4 a, float4 b, short8& hv, short8& lv) {
    float f[8] = {a.x, a.y, a.z, a.w, b.x, b.y, b.z, b.w};
#pragma unroll
    for (int i = 0; i < 8; ++i) {
        unsigned u = __float_as_uint(f[i]);
        hv[i] = (short)(u >> 16);
        float r = f[i] - __uint_as_float(u & 0xffff0000u);
        lv[i] = (short)(__float_as_uint(r) >> 16);
    }
}

__global__ __launch_bounds__(256) void k_degrees(
    const int* __restrict__ src, const int* __restrict__ dst, int E,
    int* __restrict__ outd, int* __restrict__ ind)
{
    int i = blockIdx.x * 256 + threadIdx.x;
    if (i < E) {
        atomicAdd(&outd[src[i]], 1);
        atomicAdd(&ind[dst[i]], 1);
    }
}

__global__ __launch_bounds__(256) void k_norms(
    const int* __restrict__ outd, const int* __restrict__ ind, int N,
    float* __restrict__ cs, float* __restrict__ cd, int* __restrict__ didx)
{
    int i = blockIdx.x * 256 + threadIdx.x;
    if (i < N) {
        int od = outd[i], id = ind[i];
        cs[i] = rsqrtf((float)(od > 0 ? od : 1));
        cd[i] = rsqrtf((float)(id > 0 ? id : 1));
        int d = od + id;
        didx[i] = d > 511 ? 511 : d;
    }
}

// ---- 3-phase multi-block exclusive scan of ind -> rowp, cursor ----
// phase 1: per-block (1024 elems) totals
__global__ __launch_bounds__(256) void k_scan_part(
    const int* __restrict__ ind, int N, int* __restrict__ blocksum)
{
    __shared__ int red[256];
    int t = threadIdx.x;
    int base = blockIdx.x * 1024 + t * 4;
    int s = 0;
    if (base + 3 < N) {
        int4 v = *(const int4*)(ind + base);
        s = (v.x + v.y) + (v.z + v.w);
    } else {
#pragma unroll
        for (int k = 0; k < 4; ++k) if (base + k < N) s += ind[base + k];
    }
    red[t] = s;
    __syncthreads();
    for (int off = 128; off > 0; off >>= 1) {
        if (t < off) red[t] += red[t + off];
        __syncthreads();
    }
    if (t == 0) blocksum[blockIdx.x] = red[0];
}

// phase 2: single small block scans the <=128 block totals
__global__ __launch_bounds__(128) void k_scan_mid(
    const int* __restrict__ blocksum, int nblk,
    int* __restrict__ blockoff, int* __restrict__ rowp, int N)
{
    __shared__ int sh[128];
    int t = threadIdx.x;
    int v = (t < nblk) ? blocksum[t] : 0;
    sh[t] = v;
    __syncthreads();
    for (int off = 1; off < 128; off <<= 1) {
        int x = (t >= off) ? sh[t - off] : 0;
        __syncthreads();
        sh[t] += x;
        __syncthreads();
    }
    if (t < nblk) blockoff[t] = sh[t] - v;   // exclusive
    if (t == 127) rowp[N] = sh[127];         // grand total == E
}

// phase 3: local scan + block offset -> rowp, cursor
__global__ __launch_bounds__(256) void k_scan_add(
    const int* __restrict__ ind, int N, const int* __restrict__ blockoff,
    int* __restrict__ rowp, int* __restrict__ cursor)
{
    __shared__ int sh[256];
    int t = threadIdx.x;
    int base = blockIdx.x * 1024 + t * 4;
    int v0 = 0, v1 = 0, v2 = 0, v3 = 0;
    if (base + 3 < N) {
        int4 v = *(const int4*)(ind + base);
        v0 = v.x; v1 = v.y; v2 = v.z; v3 = v.w;
    } else {
        if (base + 0 < N) v0 = ind[base + 0];
        if (base + 1 < N) v1 = ind[base + 1];
        if (base + 2 < N) v2 = ind[base + 2];
        if (base + 3 < N) v3 = ind[base + 3];
    }
    int s = (v0 + v1) + (v2 + v3);
    sh[t] = s;
    __syncthreads();
    for (int off = 1; off < 256; off <<= 1) {
        int x = (t >= off) ? sh[t - off] : 0;
        __syncthreads();
        sh[t] += x;
        __syncthreads();
    }
    int run = blockoff[blockIdx.x] + (sh[t] - s);
    if (base + 0 < N) { rowp[base + 0] = run; cursor[base + 0] = run; run += v0; }
    if (base + 1 < N) { rowp[base + 1] = run; cursor[base + 1] = run; run += v1; }
    if (base + 2 < N) { rowp[base + 2] = run; cursor[base + 2] = run; run += v2; }
    if (base + 3 < N) { rowp[base + 3] = run; cursor[base + 3] = run; run += v3; }
}

__global__ __launch_bounds__(256) void k_csrfill(
    const int* __restrict__ src, const int* __restrict__ dst, int E,
    int* __restrict__ cursor, int* __restrict__ csr)
{
    int i = blockIdx.x * 256 + threadIdx.x;
    if (i < E) {
        int pos = atomicAdd(&cursor[dst[i]], 1);
        csr[pos] = src[i];
    }
}

// WF[k][j] = sum_m projW[k][m] * W1[64+m][j]   (512x128 fp32)
__global__ __launch_bounds__(256) void k_wf(
    const float* __restrict__ projW, const float* __restrict__ W1,
    float* __restrict__ WF)
{
    int idx = blockIdx.x * 256 + threadIdx.x;
    int k = idx >> 7, j = idx & 127;
    const float* a = projW + (size_t)k * 128;
    float s = 0.f;
#pragma unroll 8
    for (int m = 0; m < 128; ++m) s = fmaf(a[m], W1[(size_t)(64 + m) * 128 + j], s);
    WF[idx] = s;
}

__global__ void k_cb(const float* __restrict__ projb, const float* __restrict__ W1,
                     float* __restrict__ cb)
{
    int j = threadIdx.x;
    float s = 0.f;
    for (int m = 0; m < 128; ++m) s = fmaf(projb[m], W1[(size_t)(64 + m) * 128 + j], s);
    cb[j] = s;
}

// WT[j][k] split hi/lo bf16; k<512: WF, k<576: W1[0:64], else W1[192:256]
__global__ __launch_bounds__(256) void k_wt1(
    const float* __restrict__ WF, const float* __restrict__ W1,
    unsigned short* __restrict__ wt_hi, unsigned short* __restrict__ wt_lo)
{
    int idx = blockIdx.x * 256 + threadIdx.x;   // 128*640
    int j = idx / 640, k = idx - j * 640;
    float v;
    if (k < 512) v = WF[(size_t)k * 128 + j];
    else if (k < 576) v = W1[(size_t)(k - 512) * 128 + j];
    else v = W1[(size_t)(192 + k - 576) * 128 + j];
    unsigned short h = f2bf(v);
    wt_hi[idx] = h;
    float r = v - bf2f(h);
    wt_lo[idx] = (unsigned short)(__float_as_uint(r) >> 16);
}

__global__ __launch_bounds__(256) void k_wt2(
    const float* __restrict__ W2,
    unsigned short* __restrict__ w2t_hi, unsigned short* __restrict__ w2t_lo)
{
    int idx = blockIdx.x * 256 + threadIdx.x;   // 64*128
    int j = idx >> 7, k = idx & 127;
    float v = W2[(size_t)k * 64 + j];
    unsigned short h = f2bf(v);
    w2t_hi[idx] = h;
    float r = v - bf2f(h);
    w2t_lo[idx] = (unsigned short)(__float_as_uint(r) >> 16);
}

// ---- k_h1: 128x128 tile, 4 waves (2x2), wave=64x64 (4x4 frags of 16x16),
//      K = 20 steps x 32, split-bf16 3-term MFMA. LDS row stride 40 elems.
__global__ __launch_bounds__(256, 2) void k_h1(
    const float* __restrict__ logits, const float* __restrict__ features,
    const float* __restrict__ deg_table, const int* __restrict__ didx,
    const unsigned short* __restrict__ wt_hi, const unsigned short* __restrict__ wt_lo,
    const float* __restrict__ cb, const float* __restrict__ cs,
    unsigned short* __restrict__ h1, int N)
{
    constexpr int NT = 20;
    __shared__ short Ah[128 * 40], Al[128 * 40], Bh[128 * 40], Bl[128 * 40];
    int tid = threadIdx.x;
    int i0 = blockIdx.x * 128;
    int sr = tid >> 1, sh = tid & 1;
    int snode = i0 + sr; if (snode >= N) snode = N - 1;
    int sdidx = didx[snode];
    int sc = tid >> 1, sq = (tid & 1) * 2;
    int lane = tid & 63, w = tid >> 6;
    int wr = w >> 1, wc = w & 1;
    int fr = lane & 15, kg = lane >> 4;
    int aoff = (wr * 64 + fr) * 40 + kg * 8;
    int boff = (wc * 64 + fr) * 40 + kg * 8;

    f32x4 acc[4][4];
#pragma unroll
    for (int ri = 0; ri < 4; ++ri)
#pragma unroll
        for (int ci = 0; ci < 4; ++ci) acc[ri][ci] = (f32x4)0.f;

    float4 fa0, fa1, fa2, fa3;
    uint4 pbh0, pbh1, pbl0, pbl1;

    auto loadT = [&](int t) {
        const float* ap;
        if (t < 16)      ap = features  + (size_t)snode * 512 + t * 32 + sh * 16;
        else if (t < 18) ap = logits    + (size_t)snode * 64 + (t - 16) * 32 + sh * 16;
        else             ap = deg_table + (size_t)sdidx * 64 + (t - 18) * 32 + sh * 16;
        fa0 = *(const float4*)(ap);
        fa1 = *(const float4*)(ap + 4);
        fa2 = *(const float4*)(ap + 8);
        fa3 = *(const float4*)(ap + 12);
        const unsigned short* bh = wt_hi + (size_t)sc * 640 + t * 32 + sq * 8;
        const unsigned short* bl = wt_lo + (size_t)sc * 640 + t * 32 + sq * 8;
        pbh0 = *(const uint4*)(bh);
        pbh1 = *(const uint4*)(bh + 8);
        pbl0 = *(const uint4*)(bl);
        pbl1 = *(const uint4*)(bl + 8);
    };
    auto writeT = [&]() {
        short8 h0, l0, h1v, l1v;
        split_f4(fa0, fa1, h0, l0);
        split_f4(fa2, fa3, h1v, l1v);
        int ao = sr * 40 + sh * 16;
        *(short8*)&Ah[ao] = h0;      *(short8*)&Ah[ao + 8] = h1v;
        *(short8*)&Al[ao] = l0;      *(short8*)&Al[ao + 8] = l1v;
        int bo = sc * 40 + sq * 8;
        *(uint4*)&Bh[bo] = pbh0;     *(uint4*)&Bh[bo + 8] = pbh1;
        *(uint4*)&Bl[bo] = pbl0;     *(uint4*)&Bl[bo + 8] = pbl1;
    };

    loadT(0);
    writeT();
    for (int t = 0; t < NT; ++t) {
        __syncthreads();
        if (t + 1 < NT) loadT(t + 1);
        short8 ah[4], al[4];
#pragma unroll
        for (int ri = 0; ri < 4; ++ri) {
            ah[ri] = *(const short8*)&Ah[aoff + ri * 640];
            al[ri] = *(const short8*)&Al[aoff + ri * 640];
        }
#pragma unroll
        for (int ci = 0; ci < 4; ++ci) {
            short8 bh = *(const short8*)&Bh[boff + ci * 640];
            short8 bl = *(const short8*)&Bl[boff + ci * 640];
#pragma unroll
            for (int ri = 0; ri < 4; ++ri) {
                acc[ri][ci] = __builtin_amdgcn_mfma_f32_16x16x32_bf16(ah[ri], bh, acc[ri][ci], 0, 0, 0);
                acc[ri][ci] = __builtin_amdgcn_mfma_f32_16x16x32_bf16(al[ri], bh, acc[ri][ci], 0, 0, 0);
                acc[ri][ci] = __builtin_amdgcn_mfma_f32_16x16x32_bf16(ah[ri], bl, acc[ri][ci], 0, 0, 0);
            }
        }
        __syncthreads();
        if (t + 1 < NT) writeT();
    }

    float cbv[4];
#pragma unroll
    for (int ci = 0; ci < 4; ++ci) cbv[ci] = cb[wc * 64 + ci * 16 + fr];
#pragma unroll
    for (int ri = 0; ri < 4; ++ri) {
#pragma unroll
        for (int j = 0; j < 4; ++j) {
            int row = i0 + wr * 64 + ri * 16 + kg * 4 + j;
            if (row < N) {
                float scv = cs[row];
#pragma unroll
                for (int ci = 0; ci < 4; ++ci) {
                    int col = wc * 64 + ci * 16 + fr;
                    h1[(size_t)row * 128 + col] = f2bf(scv * (acc[ri][ci][j] + cbv[ci]));
                }
            }
        }
    }
}

// Layer-1 aggregation: y[i] = relu( (sum_{e: dst=i} h1[src_e]) * cd[i] + b1 )
// wave per node, dword gathers (2 bf16 cols/lane), unroll 8 for MLP.
__global__ __launch_bounds__(256) void k_agg1(
    const unsigned short* __restrict__ h1, const int* __restrict__ rowp,
    const int* __restrict__ csr, const float* __restrict__ cd,
    const float* __restrict__ b1, float* __restrict__ y, int N)
{
    int i = blockIdx.x * 4 + (threadIdx.x >> 6);
    if (i >= N) return;
    int lane = threadIdx.x & 63;
    int s0 = rowp[i], s1 = rowp[i + 1];
    float ax = 0.f, ay = 0.f;
    int e = s0;
    for (; e + 8 <= s1; e += 8) {
        unsigned u0 = *(const unsigned*)(h1 + (size_t)csr[e + 0] * 128 + lane * 2);
        unsigned u1 = *(const unsigned*)(h1 + (size_t)csr[e + 1] * 128 + lane * 2);
        unsigned u2 = *(const unsigned*)(h1 + (size_t)csr[e + 2] * 128 + lane * 2);
        unsigned u3 = *(const unsigned*)(h1 + (size_t)csr[e + 3] * 128 + lane * 2);
        unsigned u4 = *(const unsigned*)(h1 + (size_t)csr[e + 4] * 128 + lane * 2);
        unsigned u5 = *(const unsigned*)(h1 + (size_t)csr[e + 5] * 128 + lane * 2);
        unsigned u6 = *(const unsigned*)(h1 + (size_t)csr[e + 6] * 128 + lane * 2);
        unsigned u7 = *(const unsigned*)(h1 + (size_t)csr[e + 7] * 128 + lane * 2);
        ax += ((__uint_as_float(u0 << 16) + __uint_as_float(u1 << 16)) +
               (__uint_as_float(u2 << 16) + __uint_as_float(u3 << 16))) +
              ((__uint_as_float(u4 << 16) + __uint_as_float(u5 << 16)) +
               (__uint_as_float(u6 << 16) + __uint_as_float(u7 << 16)));
        ay += ((__uint_as_float(u0 & 0xffff0000u) + __uint_as_float(u1 & 0xffff0000u)) +
               (__uint_as_float(u2 & 0xffff0000u) + __uint_as_float(u3 & 0xffff0000u))) +
              ((__uint_as_float(u4 & 0xffff0000u) + __uint_as_float(u5 & 0xffff0000u)) +
               (__uint_as_float(u6 & 0xffff0000u) + __uint_as_float(u7 & 0xffff0000u)));
    }
    for (; e < s1; ++e) {
        unsigned u = *(const unsigned*)(h1 + (size_t)csr[e] * 128 + lane * 2);
        ax += __uint_as_float(u << 16);
        ay += __uint_as_float(u & 0xffff0000u);
    }
    float cdi = cd[i];
    float2 o;
    o.x = fmaxf(fmaf(ax, cdi, b1[lane * 2 + 0]), 0.f);
    o.y = fmaxf(fmaf(ay, cdi, b1[lane * 2 + 1]), 0.f);
    *(float2*)(y + (size_t)i * 128 + lane * 2) = o;
}

// ---- k_h2: h2 = cs*(y@W2), 128x64 tile, wave=64x32 (4x2 frags), K=4x32.
__global__ __launch_bounds__(256, 2) void k_h2(
    const float* __restrict__ y,
    const unsigned short* __restrict__ w2t_hi, const unsigned short* __restrict__ w2t_lo,
    const float* __restrict__ cs, unsigned short* __restrict__ h2, int N)
{
    constexpr int NT = 4;
    __shared__ short Ah[128 * 40], Al[128 * 40], Bh[64 * 40], Bl[64 * 40];
    int tid = threadIdx.x;
    int i0 = blockIdx.x * 128;
    int sr = tid >> 1, sh = tid & 1;
    int snode = i0 + sr; if (snode >= N) snode = N - 1;
    const float* abase = y + (size_t)snode * 128 + sh * 16;
    int sc = tid >> 2, sq = tid & 3;
    int lane = tid & 63, w = tid >> 6;
    int wr = w >> 1, wc = w & 1;
    int fr = lane & 15, kg = lane >> 4;
    int aoff = (wr * 64 + fr) * 40 + kg * 8;
    int boff = (wc * 32 + fr) * 40 + kg * 8;

    f32x4 acc[4][2];
#pragma unroll
    for (int ri = 0; ri < 4; ++ri)
#pragma unroll
        for (int ci = 0; ci < 2; ++ci) acc[ri][ci] = (f32x4)0.f;

    float4 fa0, fa1, fa2, fa3;
    uint4 pbh0, pbl0;

    auto loadT = [&](int t) {
        const float* ap = abase + t * 32;
        fa0 = *(const float4*)(ap);
        fa1 = *(const float4*)(ap + 4);
        fa2 = *(const float4*)(ap + 8);
        fa3 = *(const float4*)(ap + 12);
        pbh0 = *(const uint4*)(w2t_hi + (size_t)sc * 128 + t * 32 + sq * 8);
        pbl0 = *(const uint4*)(w2t_lo + (size_t)sc * 128 + t * 32 + sq * 8);
    };
    auto writeT = [&]() {
        short8 h0, l0, h1v, l1v;
        split_f4(fa0, fa1, h0, l0);
        split_f4(fa2, fa3, h1v, l1v);
        int ao = sr * 40 + sh * 16;
        *(short8*)&Ah[ao] = h0;      *(short8*)&Ah[ao + 8] = h1v;
        *(short8*)&Al[ao] = l0;      *(short8*)&Al[ao + 8] = l1v;
        int bo = sc * 40 + sq * 8;
        *(uint4*)&Bh[bo] = pbh0;
        *(uint4*)&Bl[bo] = pbl0;
    };

    loadT(0);
    writeT();
    for (int t = 0; t < NT; ++t) {
        __syncthreads();
        if (t + 1 < NT) loadT(t + 1);
        short8 ah[4], al[4];
#pragma unroll
        for (int ri = 0; ri < 4; ++ri) {
            ah[ri] = *(const short8*)&Ah[aoff + ri * 640];
            al[ri] = *(const short8*)&Al[aoff + ri * 640];
        }
#pragma unroll
        for (int ci = 0; ci < 2; ++ci) {
            short8 bh = *(const short8*)&Bh[boff + ci * 640];
            short8 bl = *(const short8*)&Bl[boff + ci * 640];
#pragma unroll
            for (int ri = 0; ri < 4; ++ri) {
                acc[ri][ci] = __builtin_amdgcn_mfma_f32_16x16x32_bf16(ah[ri], bh, acc[ri][ci], 0, 0, 0);
                acc[ri][ci] = __builtin_amdgcn_mfma_f32_16x16x32_bf16(al[ri], bh, acc[ri][ci], 0, 0, 0);
                acc[ri][ci] = __builtin_amdgcn_mfma_f32_16x16x32_bf16(ah[ri], bl, acc[ri][ci], 0, 0, 0);
            }
        }
        __syncthreads();
        if (t + 1 < NT) writeT();
    }

#pragma unroll
    for (int ri = 0; ri < 4; ++ri) {
#pragma unroll
        for (int j = 0; j < 4; ++j) {
            int row = i0 + wr * 64 + ri * 16 + kg * 4 + j;
            if (row < N) {
                float scv = cs[row];
#pragma unroll
                for (int ci = 0; ci < 2; ++ci) {
                    int col = wc * 32 + ci * 16 + fr;
                    h2[(size_t)row * 64 + col] = f2bf(scv * acc[ri][ci][j]);
                }
            }
        }
    }
}

// Layer-2 aggregation: out[i] = (sum h2[src_e]) * cd[i] + b2
// 32-lane half-wave per node (dword = 2 bf16 cols per lane), unroll 8.
__global__ __launch_bounds__(256) void k_agg2(
    const unsigned short* __restrict__ h2, const int* __restrict__ rowp,
    const int* __restrict__ csr, const float* __restrict__ cd,
    const float* __restrict__ b2, float* __restrict__ out, int N)
{
    int i = blockIdx.x * 8 + (threadIdx.x >> 5);
    if (i >= N) return;
    int lane = threadIdx.x & 31;
    int s0 = rowp[i], s1 = rowp[i + 1];
    float ax = 0.f, ay = 0.f;
    int e = s0;
    for (; e + 8 <= s1; e += 8) {
        unsigned u0 = *(const unsigned*)(h2 + (size_t)csr[e + 0] * 64 + lane * 2);
        unsigned u1 = *(const unsigned*)(h2 + (size_t)csr[e + 1] * 64 + lane * 2);
        unsigned u2 = *(const unsigned*)(h2 + (size_t)csr[e + 2] * 64 + lane * 2);
        unsigned u3 = *(const unsigned*)(h2 + (size_t)csr[e + 3] * 64 + lane * 2);
        unsigned u4 = *(const unsigned*)(h2 + (size_t)csr[e + 4] * 64 + lane * 2);
        unsigned u5 = *(const unsigned*)(h2 + (size_t)csr[e + 5] * 64 + lane * 2);
        unsigned u6 = *(const unsigned*)(h2 + (size_t)csr[e + 6] * 64 + lane * 2);
        unsigned u7 = *(const unsigned*)(h2 + (size_t)csr[e + 7] * 64 + lane * 2);
        ax += ((__uint_as_float(u0 << 16) + __uint_as_float(u1 << 16)) +
               (__uint_as_float(u2 << 16) + __uint_as_float(u3 << 16))) +
              ((__uint_as_float(u4 << 16) + __uint_as_float(u5 << 16)) +
               (__uint_as_float(u6 << 16) + __uint_as_float(u7 << 16)));
        ay += ((__uint_as_float(u0 & 0xffff0000u) + __uint_as_float(u1 & 0xffff0000u)) +
               (__uint_as_float(u2 & 0xffff0000u) + __uint_as_float(u3 & 0xffff0000u))) +
              ((__uint_as_float(u4 & 0xffff0000u) + __uint_as_float(u5 & 0xffff0000u)) +
               (__uint_as_float(u6 & 0xffff0000u) + __uint_as_float(u7 & 0xffff0000u)));
    }
    for (; e < s1; ++e) {
        unsigned u = *(const unsigned*)(h2 + (size_t)csr[e] * 64 + lane * 2);
        ax += __uint_as_float(u << 16);
        ay += __uint_as_float(u & 0xffff0000u);
    }
    float cdi = cd[i];
    float2 o;
    o.x = fmaf(ax, cdi, b2[lane * 2 + 0]);
    o.y = fmaf(ay, cdi, b2[lane * 2 + 1]);
    *(float2*)(out + (size_t)i * 64 + lane * 2) = o;
}

extern "C" void kernel_launch(void* const* d_in, const int* in_sizes, int n_in,
                              void* d_out, int out_size, void* d_ws, size_t ws_size,
                              hipStream_t stream)
{
    const int* src = (const int*)d_in[0];
    const int* dst = (const int*)d_in[1];
    const float* logits = (const float*)d_in[2];
    const float* features = (const float*)d_in[3];
    const float* projW = (const float*)d_in[4];
    const float* projb = (const float*)d_in[5];
    const float* deg_table = (const float*)d_in[6];
    const float* W1 = (const float*)d_in[7];
    const float* b1 = (const float*)d_in[8];
    const float* W2 = (const float*)d_in[9];
    const float* b2 = (const float*)d_in[10];
    const int E = in_sizes[0];
    const int N = in_sizes[2] / 64;

    char* base = (char*)d_ws;
    size_t off = 0;
    auto alloc = [&](size_t bytes) -> void* {
        void* p = base + off;
        off += (bytes + 255) & ~(size_t)255;
        return p;
    };
    int* outd   = (int*)alloc((size_t)N * 4);
    int* ind    = (int*)alloc((size_t)N * 4);
    int* rowp   = (int*)alloc((size_t)(N + 1) * 4);
    int* cursor = (int*)alloc((size_t)N * 4);
    int* csr    = (int*)alloc((size_t)E * 4);
    int* didx   = (int*)alloc((size_t)N * 4);
    float* cs   = (float*)alloc((size_t)N * 4);
    float* cd   = (float*)alloc((size_t)N * 4);
    float* WF   = (float*)alloc((size_t)512 * 128 * 4);
    float* cb   = (float*)alloc((size_t)128 * 4);
    int* blocksum = (int*)alloc(128 * 4);
    int* blockoff = (int*)alloc(128 * 4);
    unsigned short* wt_hi  = (unsigned short*)alloc((size_t)128 * 640 * 2);
    unsigned short* wt_lo  = (unsigned short*)alloc((size_t)128 * 640 * 2);
    unsigned short* w2t_hi = (unsigned short*)alloc((size_t)64 * 128 * 2);
    unsigned short* w2t_lo = (unsigned short*)alloc((size_t)64 * 128 * 2);
    unsigned short* h1 = (unsigned short*)alloc((size_t)N * 128 * 2);
    float* yb   = (float*)alloc((size_t)N * 128 * 4);
    unsigned short* h2 = h1;   // h1 dead after k_agg1; reuse
    float* outp = (float*)d_out;

    hipMemsetAsync(outd, 0, (size_t)N * 4, stream);
    hipMemsetAsync(ind, 0, (size_t)N * 4, stream);

    int eb = (E + 255) / 256;
    int nb = (N + 255) / 256;
    int mb = (N + 127) / 128;
    int nscan = (N + 1023) / 1024;   // <=128 for N<=131072

    k_degrees<<<eb, 256, 0, stream>>>(src, dst, E, outd, ind);
    k_norms<<<nb, 256, 0, stream>>>(outd, ind, N, cs, cd, didx);
    k_scan_part<<<nscan, 256, 0, stream>>>(ind, N, blocksum);
    k_scan_mid<<<1, 128, 0, stream>>>(blocksum, nscan, blockoff, rowp, N);
    k_scan_add<<<nscan, 256, 0, stream>>>(ind, N, blockoff, rowp, cursor);
    k_csrfill<<<eb, 256, 0, stream>>>(src, dst, E, cursor, csr);
    k_wf<<<256, 256, 0, stream>>>(projW, W1, WF);
    k_cb<<<1, 128, 0, stream>>>(projb, W1, cb);
    k_wt1<<<320, 256, 0, stream>>>(WF, W1, wt_hi, wt_lo);
    k_wt2<<<32, 256, 0, stream>>>(W2, w2t_hi, w2t_lo);
    k_h1<<<mb, 256, 0, stream>>>(logits, features, deg_table, didx, wt_hi, wt_lo, cb, cs, h1, N);
    k_agg1<<<(N + 3) / 4, 256, 0, stream>>>(h1, rowp, csr, cd, b1, yb, N);
    k_h2<<<mb, 256, 0, stream>>>(yb, w2t_hi, w2t_lo, cs, h2, N);
    k_agg2<<<(N + 7) / 8, 256, 0, stream>>>(h2, rowp, csr, cd, b2, outp, N);
}

// Round 7
// 438.270 us; speedup vs baseline: 3.6802x; 1.1781x over previous
//
#include <hip/hip_runtime.h>
#include <cstdint>
#include <cstddef>

// ---------------------------------------------------------------------------
// GCN forward, MFMA edition:
//   deg -> cs/cd/didx -> rowp scan -> bucketed CSR build -> WF=projW@W1mid
//   -> WT hi/lo bf16 -> h1 = cs*(x@W1+cb) [split-bf16 3-term MFMA]
//   -> agg1 -> y = relu(agg1*cd+b1) -> h2 = cs*(y@W2) -> agg2 -> out
// Split trick: a = a_hi + a_lo (bf16 trunc + bf16 residual);
// D = ahi*bhi + alo*bhi + ahi*blo -> only O(2^-17) rel. terms dropped.
// R6 lessons: (1) edge-atomic csrfill = 105MB HBM writes for a 6.4MB array
// (scattered 4B stores across 8 XCD L2s) -> bucketed 2-pass build where each
// 1024-node bucket's csr region is filled by ONE block (L2-local, full-line
// writebacks). Bucket offsets are free: boff[b] = rowp[b<<10].
// (2) stride-40 LDS still 4-way conflicts (8M) -> XOR swizzle
// chunk' = chunk ^ (row&3) on 16B chunks, row stride 32 shorts: bank-uniform
// for both staged writes (chunks {s, s+2} per thread) and b128 frag reads.
// (3) double-buffered LDS -> ONE barrier per K-step (write next-buf pre-
// barrier is safe: its readers finished before the previous barrier).
// R4 lesson: don't cap VGPRs below acc needs (spill -> scratch traffic).
// ---------------------------------------------------------------------------

typedef short short8 __attribute__((ext_vector_type(8)));
typedef float f32x4 __attribute__((ext_vector_type(4)));

__device__ __forceinline__ unsigned short f2bf(float f) {
    unsigned u = __float_as_uint(f);
    u += 0x7fff + ((u >> 16) & 1);   // RNE
    return (unsigned short)(u >> 16);
}
__device__ __forceinline__ float bf2f(unsigned short s) {
    return __uint_as_float(((unsigned)s) << 16);
}

__device__ __forceinline__ void split_f4(float4 a, float4 b, short8& hv, short8& lv) {
    float f[8] = {a.x, a.y, a.z, a.w, b.x, b.y, b.z, b.w};
#pragma unroll
    for (int i = 0; i < 8; ++i) {
        unsigned u = __float_as_uint(f[i]);
        hv[i] = (short)(u >> 16);
        float r = f[i] - __uint_as_float(u & 0xffff0000u);
        lv[i] = (short)(__float_as_uint(r) >> 16);
    }
}

__global__ __launch_bounds__(256) void k_degrees(
    const int* __restrict__ src, const int* __restrict__ dst, int E,
    int* __restrict__ outd, int* __restrict__ ind)
{
    int i = blockIdx.x * 256 + threadIdx.x;
    if (i < E) {
        atomicAdd(&outd[src[i]], 1);
        atomicAdd(&ind[dst[i]], 1);
    }
}

__global__ __launch_bounds__(256) void k_norms(
    const int* __restrict__ outd, const int* __restrict__ ind, int N,
    float* __restrict__ cs, float* __restrict__ cd, int* __restrict__ didx)
{
    int i = blockIdx.x * 256 + threadIdx.x;
    if (i < N) {
        int od = outd[i], id = ind[i];
        cs[i] = rsqrtf((float)(od > 0 ? od : 1));
        cd[i] = rsqrtf((float)(id > 0 ? id : 1));
        int d = od + id;
        didx[i] = d > 511 ? 511 : d;
    }
}

// ---- 3-phase multi-block exclusive scan of ind -> rowp ----
__global__ __launch_bounds__(256) void k_scan_part(
    const int* __restrict__ ind, int N, int* __restrict__ blocksum)
{
    __shared__ int red[256];
    int t = threadIdx.x;
    int base = blockIdx.x * 1024 + t * 4;
    int s = 0;
    if (base + 3 < N) {
        int4 v = *(const int4*)(ind + base);
        s = (v.x + v.y) + (v.z + v.w);
    } else {
#pragma unroll
        for (int k = 0; k < 4; ++k) if (base + k < N) s += ind[base + k];
    }
    red[t] = s;
    __syncthreads();
    for (int off = 128; off > 0; off >>= 1) {
        if (t < off) red[t] += red[t + off];
        __syncthreads();
    }
    if (t == 0) blocksum[blockIdx.x] = red[0];
}

__global__ __launch_bounds__(128) void k_scan_mid(
    const int* __restrict__ blocksum, int nblk,
    int* __restrict__ blockoff, int* __restrict__ rowp, int N)
{
    __shared__ int sh[128];
    int t = threadIdx.x;
    int v = (t < nblk) ? blocksum[t] : 0;
    sh[t] = v;
    __syncthreads();
    for (int off = 1; off < 128; off <<= 1) {
        int x = (t >= off) ? sh[t - off] : 0;
        __syncthreads();
        sh[t] += x;
        __syncthreads();
    }
    if (t < nblk) blockoff[t] = sh[t] - v;   // exclusive
    if (t == 127) rowp[N] = sh[127];         // grand total == E
}

__global__ __launch_bounds__(256) void k_scan_add(
    const int* __restrict__ ind, int N, const int* __restrict__ blockoff,
    int* __restrict__ rowp)
{
    __shared__ int sh[256];
    int t = threadIdx.x;
    int base = blockIdx.x * 1024 + t * 4;
    int v0 = 0, v1 = 0, v2 = 0, v3 = 0;
    if (base + 3 < N) {
        int4 v = *(const int4*)(ind + base);
        v0 = v.x; v1 = v.y; v2 = v.z; v3 = v.w;
    } else {
        if (base + 0 < N) v0 = ind[base + 0];
        if (base + 1 < N) v1 = ind[base + 1];
        if (base + 2 < N) v2 = ind[base + 2];
        if (base + 3 < N) v3 = ind[base + 3];
    }
    int s = (v0 + v1) + (v2 + v3);
    sh[t] = s;
    __syncthreads();
    for (int off = 1; off < 256; off <<= 1) {
        int x = (t >= off) ? sh[t - off] : 0;
        __syncthreads();
        sh[t] += x;
        __syncthreads();
    }
    int run = blockoff[blockIdx.x] + (sh[t] - s);
    if (base + 0 < N) { rowp[base + 0] = run; run += v0; }
    if (base + 1 < N) { rowp[base + 1] = run; run += v1; }
    if (base + 2 < N) { rowp[base + 2] = run; run += v2; }
    if (base + 3 < N) { rowp[base + 3] = run; run += v3; }
}

// ---- bucketed CSR build: bucket b = 1024-node range; region = rowp[b<<10] ----
__global__ __launch_bounds__(128) void k_binit(
    const int* __restrict__ rowp, int* __restrict__ bcur, int nb)
{
    int b = blockIdx.x * 128 + threadIdx.x;
    if (b < nb) bcur[b] = rowp[b << 10];
}

// scatter edges into bucket regions of ebuf, block-privatized reservations
__global__ __launch_bounds__(256) void k_cscatter(
    const int* __restrict__ src, const int* __restrict__ dst, int E,
    int* __restrict__ bcur, unsigned* __restrict__ ebuf, int nb)
{
    __shared__ int hist[128];
    __shared__ int base[128];
    int t = threadIdx.x;
    int e0 = blockIdx.x * 4096;
    if (t < 128) hist[t] = 0;
    __syncthreads();
    int s_[16], d_[16];
#pragma unroll
    for (int i = 0; i < 16; ++i) {
        int idx = e0 + t + i * 256;
        if (idx < E) {
            s_[i] = src[idx];
            d_[i] = dst[idx];
            atomicAdd(&hist[d_[i] >> 10], 1);
        } else d_[i] = -1;
    }
    __syncthreads();
    if (t < nb && hist[t] > 0) base[t] = atomicAdd(&bcur[t], hist[t]);
    __syncthreads();
    if (t < 128) hist[t] = 0;
    __syncthreads();
#pragma unroll
    for (int i = 0; i < 16; ++i) {
        if (d_[i] >= 0) {
            int b = d_[i] >> 10;
            int p = base[b] + atomicAdd(&hist[b], 1);
            ebuf[p] = (unsigned)s_[i] | ((unsigned)(d_[i] & 1023) << 17);
        }
    }
}

// one block per bucket: sort bucket's edges into csr via LDS cursors
__global__ __launch_bounds__(512) void k_cbuild(
    const unsigned* __restrict__ ebuf, const int* __restrict__ rowp,
    int* __restrict__ csr, int N)
{
    __shared__ int cur[1024];
    int nb0 = blockIdx.x << 10;
    int ncnt = min(1024, N - nb0);
    int t = threadIdx.x;
    for (int i = t; i < ncnt; i += 512) cur[i] = rowp[nb0 + i];
    __syncthreads();
    int lo = rowp[nb0], hi = rowp[nb0 + ncnt];
    for (int idx = lo + t; idx < hi; idx += 512) {
        unsigned e = ebuf[idx];
        int p = atomicAdd(&cur[e >> 17], 1);
        csr[p] = (int)(e & 0x1FFFF);
    }
}

// WF[k][j] = sum_m projW[k][m] * W1[64+m][j]   (512x128 fp32)
__global__ __launch_bounds__(256) void k_wf(
    const float* __restrict__ projW, const float* __restrict__ W1,
    float* __restrict__ WF)
{
    int idx = blockIdx.x * 256 + threadIdx.x;
    int k = idx >> 7, j = idx & 127;
    const float* a = projW + (size_t)k * 128;
    float s = 0.f;
#pragma unroll 8
    for (int m = 0; m < 128; ++m) s = fmaf(a[m], W1[(size_t)(64 + m) * 128 + j], s);
    WF[idx] = s;
}

__global__ void k_cb(const float* __restrict__ projb, const float* __restrict__ W1,
                     float* __restrict__ cb)
{
    int j = threadIdx.x;
    float s = 0.f;
    for (int m = 0; m < 128; ++m) s = fmaf(projb[m], W1[(size_t)(64 + m) * 128 + j], s);
    cb[j] = s;
}

// WT[j][k] split hi/lo bf16; k<512: WF, k<576: W1[0:64], else W1[192:256]
__global__ __launch_bounds__(256) void k_wt1(
    const float* __restrict__ WF, const float* __restrict__ W1,
    unsigned short* __restrict__ wt_hi, unsigned short* __restrict__ wt_lo)
{
    int idx = blockIdx.x * 256 + threadIdx.x;   // 128*640
    int j = idx / 640, k = idx - j * 640;
    float v;
    if (k < 512) v = WF[(size_t)k * 128 + j];
    else if (k < 576) v = W1[(size_t)(k - 512) * 128 + j];
    else v = W1[(size_t)(192 + k - 576) * 128 + j];
    unsigned short h = f2bf(v);
    wt_hi[idx] = h;
    float r = v - bf2f(h);
    wt_lo[idx] = (unsigned short)(__float_as_uint(r) >> 16);
}

__global__ __launch_bounds__(256) void k_wt2(
    const float* __restrict__ W2,
    unsigned short* __restrict__ w2t_hi, unsigned short* __restrict__ w2t_lo)
{
    int idx = blockIdx.x * 256 + threadIdx.x;   // 64*128
    int j = idx >> 7, k = idx & 127;
    float v = W2[(size_t)k * 64 + j];
    unsigned short h = f2bf(v);
    w2t_hi[idx] = h;
    float r = v - bf2f(h);
    w2t_lo[idx] = (unsigned short)(__float_as_uint(r) >> 16);
}

// ---- k_h1: 128x128 tile, 4 waves (2x2), wave=64x64 (4x4 frags of 16x16),
// K = 20 steps x 32, split-bf16 3-term MFMA.
// LDS: [buf][row][k], row stride 32 shorts, 16B-chunk XOR swizzle
// chunk' = chunk ^ (row&3). Double-buffered, one barrier per K-step.
__global__ __launch_bounds__(256, 2) void k_h1(
    const float* __restrict__ logits, const float* __restrict__ features,
    const float* __restrict__ deg_table, const int* __restrict__ didx,
    const unsigned short* __restrict__ wt_hi, const unsigned short* __restrict__ wt_lo,
    const float* __restrict__ cb, const float* __restrict__ cs,
    unsigned short* __restrict__ h1, int N)
{
    constexpr int NT = 20;
    __shared__ __align__(16) short Ah[2][128 * 32];
    __shared__ __align__(16) short Al[2][128 * 32];
    __shared__ __align__(16) short Bh[2][128 * 32];
    __shared__ __align__(16) short Bl[2][128 * 32];
    int tid = threadIdx.x;
    int i0 = blockIdx.x * 128;
    // staging: row sr = tid>>1, chunk pair {s, s+2} with s = tid&1
    int sr = tid >> 1, shh = tid & 1;
    int snode = i0 + sr; if (snode >= N) snode = N - 1;
    int sdidx = didx[snode];
    int wo0 = sr * 32 + ((shh    ) ^ (sr & 3)) * 8;
    int wo1 = sr * 32 + ((shh + 2) ^ (sr & 3)) * 8;
    // compute
    int lane = tid & 63, w = tid >> 6;
    int wr = w >> 1, wc = w & 1;
    int fr = lane & 15, kg = lane >> 4;
    int aoff = (wr * 64 + fr) * 32 + (kg ^ (fr & 3)) * 8;  // +ri*512 (ri*16 rows)
    int boff = (wc * 64 + fr) * 32 + (kg ^ (fr & 3)) * 8;

    f32x4 acc[4][4];
#pragma unroll
    for (int ri = 0; ri < 4; ++ri)
#pragma unroll
        for (int ci = 0; ci < 4; ++ci) acc[ri][ci] = (f32x4)0.f;

    float4 fa0, fa1, fa2, fa3;
    uint4 pbh0, pbh1, pbl0, pbl1;

    auto loadT = [&](int t) {
        const float* ap;
        if (t < 16)      ap = features  + (size_t)snode * 512 + t * 32;
        else if (t < 18) ap = logits    + (size_t)snode * 64 + (t - 16) * 32;
        else             ap = deg_table + (size_t)sdidx * 64 + (t - 18) * 32;
        ap += shh * 8;
        fa0 = *(const float4*)(ap);          // chunk shh   (k 8s..8s+8)
        fa1 = *(const float4*)(ap + 4);
        fa2 = *(const float4*)(ap + 16);     // chunk shh+2
        fa3 = *(const float4*)(ap + 20);
        const unsigned short* bh = wt_hi + (size_t)sr * 640 + t * 32 + shh * 8;
        const unsigned short* bl = wt_lo + (size_t)sr * 640 + t * 32 + shh * 8;
        pbh0 = *(const uint4*)(bh);
        pbh1 = *(const uint4*)(bh + 16);
        pbl0 = *(const uint4*)(bl);
        pbl1 = *(const uint4*)(bl + 16);
    };
    auto writeT = [&](int buf) {
        short8 h0, l0, h1v, l1v;
        split_f4(fa0, fa1, h0, l0);
        split_f4(fa2, fa3, h1v, l1v);
        *(short8*)&Ah[buf][wo0] = h0;   *(short8*)&Ah[buf][wo1] = h1v;
        *(short8*)&Al[buf][wo0] = l0;   *(short8*)&Al[buf][wo1] = l1v;
        *(uint4*)&Bh[buf][wo0] = pbh0;  *(uint4*)&Bh[buf][wo1] = pbh1;
        *(uint4*)&Bl[buf][wo0] = pbl0;  *(uint4*)&Bl[buf][wo1] = pbl1;
    };

    loadT(0);
    writeT(0);
    __syncthreads();
    for (int t = 0; t < NT; ++t) {
        if (t + 1 < NT) loadT(t + 1);
        int cbuf = t & 1;
        short8 ah[4], al[4];
#pragma unroll
        for (int ri = 0; ri < 4; ++ri) {
            ah[ri] = *(const short8*)&Ah[cbuf][aoff + ri * 512];
            al[ri] = *(const short8*)&Al[cbuf][aoff + ri * 512];
        }
#pragma unroll
        for (int ci = 0; ci < 4; ++ci) {
            short8 bh = *(const short8*)&Bh[cbuf][boff + ci * 512];
            short8 bl = *(const short8*)&Bl[cbuf][boff + ci * 512];
#pragma unroll
            for (int ri = 0; ri < 4; ++ri) {
                acc[ri][ci] = __builtin_amdgcn_mfma_f32_16x16x32_bf16(ah[ri], bh, acc[ri][ci], 0, 0, 0);
                acc[ri][ci] = __builtin_amdgcn_mfma_f32_16x16x32_bf16(al[ri], bh, acc[ri][ci], 0, 0, 0);
                acc[ri][ci] = __builtin_amdgcn_mfma_f32_16x16x32_bf16(ah[ri], bl, acc[ri][ci], 0, 0, 0);
            }
        }
        if (t + 1 < NT) writeT((t + 1) & 1);   // other buffer: safe pre-barrier
        __syncthreads();
    }

    // C/D layout: col = lane&15, row = (lane>>4)*4 + reg  [m89]
    float cbv[4];
#pragma unroll
    for (int ci = 0; ci < 4; ++ci) cbv[ci] = cb[wc * 64 + ci * 16 + fr];
#pragma unroll
    for (int ri = 0; ri < 4; ++ri) {
#pragma unroll
        for (int j = 0; j < 4; ++j) {
            int row = i0 + wr * 64 + ri * 16 + kg * 4 + j;
            if (row < N) {
                float scv = cs[row];
#pragma unroll
                for (int ci = 0; ci < 4; ++ci) {
                    int col = wc * 64 + ci * 16 + fr;
                    h1[(size_t)row * 128 + col] = f2bf(scv * (acc[ri][ci][j] + cbv[ci]));
                }
            }
        }
    }
}

// Layer-1 aggregation: y[i] = relu( (sum_{e: dst=i} h1[src_e]) * cd[i] + b1 )
__global__ __launch_bounds__(256) void k_agg1(
    const unsigned short* __restrict__ h1, const int* __restrict__ rowp,
    const int* __restrict__ csr, const float* __restrict__ cd,
    const float* __restrict__ b1, float* __restrict__ y, int N)
{
    int i = blockIdx.x * 4 + (threadIdx.x >> 6);
    if (i >= N) return;
    int lane = threadIdx.x & 63;
    int s0 = rowp[i], s1 = rowp[i + 1];
    float ax = 0.f, ay = 0.f;
    int e = s0;
    for (; e + 8 <= s1; e += 8) {
        unsigned u0 = *(const unsigned*)(h1 + (size_t)csr[e + 0] * 128 + lane * 2);
        unsigned u1 = *(const unsigned*)(h1 + (size_t)csr[e + 1] * 128 + lane * 2);
        unsigned u2 = *(const unsigned*)(h1 + (size_t)csr[e + 2] * 128 + lane * 2);
        unsigned u3 = *(const unsigned*)(h1 + (size_t)csr[e + 3] * 128 + lane * 2);
        unsigned u4 = *(const unsigned*)(h1 + (size_t)csr[e + 4] * 128 + lane * 2);
        unsigned u5 = *(const unsigned*)(h1 + (size_t)csr[e + 5] * 128 + lane * 2);
        unsigned u6 = *(const unsigned*)(h1 + (size_t)csr[e + 6] * 128 + lane * 2);
        unsigned u7 = *(const unsigned*)(h1 + (size_t)csr[e + 7] * 128 + lane * 2);
        ax += ((__uint_as_float(u0 << 16) + __uint_as_float(u1 << 16)) +
               (__uint_as_float(u2 << 16) + __uint_as_float(u3 << 16))) +
              ((__uint_as_float(u4 << 16) + __uint_as_float(u5 << 16)) +
               (__uint_as_float(u6 << 16) + __uint_as_float(u7 << 16)));
        ay += ((__uint_as_float(u0 & 0xffff0000u) + __uint_as_float(u1 & 0xffff0000u)) +
               (__uint_as_float(u2 & 0xffff0000u) + __uint_as_float(u3 & 0xffff0000u))) +
              ((__uint_as_float(u4 & 0xffff0000u) + __uint_as_float(u5 & 0xffff0000u)) +
               (__uint_as_float(u6 & 0xffff0000u) + __uint_as_float(u7 & 0xffff0000u)));
    }
    for (; e < s1; ++e) {
        unsigned u = *(const unsigned*)(h1 + (size_t)csr[e] * 128 + lane * 2);
        ax += __uint_as_float(u << 16);
        ay += __uint_as_float(u & 0xffff0000u);
    }
    float cdi = cd[i];
    float2 o;
    o.x = fmaxf(fmaf(ax, cdi, b1[lane * 2 + 0]), 0.f);
    o.y = fmaxf(fmaf(ay, cdi, b1[lane * 2 + 1]), 0.f);
    *(float2*)(y + (size_t)i * 128 + lane * 2) = o;
}

// ---- k_h2: h2 = cs*(y@W2), 128x64 tile, wave=64x32 (4x2 frags), K=4x32.
__global__ __launch_bounds__(256, 2) void k_h2(
    const float* __restrict__ y,
    const unsigned short* __restrict__ w2t_hi, const unsigned short* __restrict__ w2t_lo,
    const float* __restrict__ cs, unsigned short* __restrict__ h2, int N)
{
    constexpr int NT = 4;
    __shared__ __align__(16) short Ah[2][128 * 32];
    __shared__ __align__(16) short Al[2][128 * 32];
    __shared__ __align__(16) short Bh[2][64 * 32];
    __shared__ __align__(16) short Bl[2][64 * 32];
    int tid = threadIdx.x;
    int i0 = blockIdx.x * 128;
    int sr = tid >> 1, shh = tid & 1;
    int snode = i0 + sr; if (snode >= N) snode = N - 1;
    const float* abase = y + (size_t)snode * 128 + shh * 8;
    int awo0 = sr * 32 + ((shh    ) ^ (sr & 3)) * 8;
    int awo1 = sr * 32 + ((shh + 2) ^ (sr & 3)) * 8;
    int brow_s = tid >> 2, bc = tid & 3;     // 64 rows x 4 chunks
    int bwo = brow_s * 32 + (bc ^ (brow_s & 3)) * 8;
    int lane = tid & 63, w = tid >> 6;
    int wr = w >> 1, wc = w & 1;
    int fr = lane & 15, kg = lane >> 4;
    int aoff = (wr * 64 + fr) * 32 + (kg ^ (fr & 3)) * 8;
    int boff = (wc * 32 + fr) * 32 + (kg ^ (fr & 3)) * 8;

    f32x4 acc[4][2];
#pragma unroll
    for (int ri = 0; ri < 4; ++ri)
#pragma unroll
        for (int ci = 0; ci < 2; ++ci) acc[ri][ci] = (f32x4)0.f;

    float4 fa0, fa1, fa2, fa3;
    uint4 pbh0, pbl0;

    auto loadT = [&](int t) {
        const float* ap = abase + t * 32;
        fa0 = *(const float4*)(ap);
        fa1 = *(const float4*)(ap + 4);
        fa2 = *(const float4*)(ap + 16);
        fa3 = *(const float4*)(ap + 20);
        pbh0 = *(const uint4*)(w2t_hi + (size_t)brow_s * 128 + t * 32 + bc * 8);
        pbl0 = *(const uint4*)(w2t_lo + (size_t)brow_s * 128 + t * 32 + bc * 8);
    };
    auto writeT = [&](int buf) {
        short8 h0, l0, h1v, l1v;
        split_f4(fa0, fa1, h0, l0);
        split_f4(fa2, fa3, h1v, l1v);
        *(short8*)&Ah[buf][awo0] = h0;  *(short8*)&Ah[buf][awo1] = h1v;
        *(short8*)&Al[buf][awo0] = l0;  *(short8*)&Al[buf][awo1] = l1v;
        *(uint4*)&Bh[buf][bwo] = pbh0;
        *(uint4*)&Bl[buf][bwo] = pbl0;
    };

    loadT(0);
    writeT(0);
    __syncthreads();
    for (int t = 0; t < NT; ++t) {
        if (t + 1 < NT) loadT(t + 1);
        int cbuf = t & 1;
        short8 ah[4], al[4];
#pragma unroll
        for (int ri = 0; ri < 4; ++ri) {
            ah[ri] = *(const short8*)&Ah[cbuf][aoff + ri * 512];
            al[ri] = *(const short8*)&Al[cbuf][aoff + ri * 512];
        }
#pragma unroll
        for (int ci = 0; ci < 2; ++ci) {
            short8 bh = *(const short8*)&Bh[cbuf][boff + ci * 512];
            short8 bl = *(const short8*)&Bl[cbuf][boff + ci * 512];
#pragma unroll
            for (int ri = 0; ri < 4; ++ri) {
                acc[ri][ci] = __builtin_amdgcn_mfma_f32_16x16x32_bf16(ah[ri], bh, acc[ri][ci], 0, 0, 0);
                acc[ri][ci] = __builtin_amdgcn_mfma_f32_16x16x32_bf16(al[ri], bh, acc[ri][ci], 0, 0, 0);
                acc[ri][ci] = __builtin_amdgcn_mfma_f32_16x16x32_bf16(ah[ri], bl, acc[ri][ci], 0, 0, 0);
            }
        }
        if (t + 1 < NT) writeT((t + 1) & 1);
        __syncthreads();
    }

#pragma unroll
    for (int ri = 0; ri < 4; ++ri) {
#pragma unroll
        for (int j = 0; j < 4; ++j) {
            int row = i0 + wr * 64 + ri * 16 + kg * 4 + j;
            if (row < N) {
                float scv = cs[row];
#pragma unroll
                for (int ci = 0; ci < 2; ++ci) {
                    int col = wc * 32 + ci * 16 + fr;
                    h2[(size_t)row * 64 + col] = f2bf(scv * acc[ri][ci][j]);
                }
            }
        }
    }
}

// Layer-2 aggregation: out[i] = (sum h2[src_e]) * cd[i] + b2
__global__ __launch_bounds__(256) void k_agg2(
    const unsigned short* __restrict__ h2, const int* __restrict__ rowp,
    const int* __restrict__ csr, const float* __restrict__ cd,
    const float* __restrict__ b2, float* __restrict__ out, int N)
{
    int i = blockIdx.x * 8 + (threadIdx.x >> 5);
    if (i >= N) return;
    int lane = threadIdx.x & 31;
    int s0 = rowp[i], s1 = rowp[i + 1];
    float ax = 0.f, ay = 0.f;
    int e = s0;
    for (; e + 8 <= s1; e += 8) {
        unsigned u0 = *(const unsigned*)(h2 + (size_t)csr[e + 0] * 64 + lane * 2);
        unsigned u1 = *(const unsigned*)(h2 + (size_t)csr[e + 1] * 64 + lane * 2);
        unsigned u2 = *(const unsigned*)(h2 + (size_t)csr[e + 2] * 64 + lane * 2);
        unsigned u3 = *(const unsigned*)(h2 + (size_t)csr[e + 3] * 64 + lane * 2);
        unsigned u4 = *(const unsigned*)(h2 + (size_t)csr[e + 4] * 64 + lane * 2);
        unsigned u5 = *(const unsigned*)(h2 + (size_t)csr[e + 5] * 64 + lane * 2);
        unsigned u6 = *(const unsigned*)(h2 + (size_t)csr[e + 6] * 64 + lane * 2);
        unsigned u7 = *(const unsigned*)(h2 + (size_t)csr[e + 7] * 64 + lane * 2);
        ax += ((__uint_as_float(u0 << 16) + __uint_as_float(u1 << 16)) +
               (__uint_as_float(u2 << 16) + __uint_as_float(u3 << 16))) +
              ((__uint_as_float(u4 << 16) + __uint_as_float(u5 << 16)) +
               (__uint_as_float(u6 << 16) + __uint_as_float(u7 << 16)));
        ay += ((__uint_as_float(u0 & 0xffff0000u) + __uint_as_float(u1 & 0xffff0000u)) +
               (__uint_as_float(u2 & 0xffff0000u) + __uint_as_float(u3 & 0xffff0000u))) +
              ((__uint_as_float(u4 & 0xffff0000u) + __uint_as_float(u5 & 0xffff0000u)) +
               (__uint_as_float(u6 & 0xffff0000u) + __uint_as_float(u7 & 0xffff0000u)));
    }
    for (; e < s1; ++e) {
        unsigned u = *(const unsigned*)(h2 + (size_t)csr[e] * 64 + lane * 2);
        ax += __uint_as_float(u << 16);
        ay += __uint_as_float(u & 0xffff0000u);
    }
    float cdi = cd[i];
    float2 o;
    o.x = fmaf(ax, cdi, b2[lane * 2 + 0]);
    o.y = fmaf(ay, cdi, b2[lane * 2 + 1]);
    *(float2*)(out + (size_t)i * 64 + lane * 2) = o;
}

extern "C" void kernel_launch(void* const* d_in, const int* in_sizes, int n_in,
                              void* d_out, int out_size, void* d_ws, size_t ws_size,
                              hipStream_t stream)
{
    const int* src = (const int*)d_in[0];
    const int* dst = (const int*)d_in[1];
    const float* logits = (const float*)d_in[2];
    const float* features = (const float*)d_in[3];
    const float* projW = (const float*)d_in[4];
    const float* projb = (const float*)d_in[5];
    const float* deg_table = (const float*)d_in[6];
    const float* W1 = (const float*)d_in[7];
    const float* b1 = (const float*)d_in[8];
    const float* W2 = (const float*)d_in[9];
    const float* b2 = (const float*)d_in[10];
    const int E = in_sizes[0];
    const int N = in_sizes[2] / 64;

    char* base = (char*)d_ws;
    size_t off = 0;
    auto alloc = [&](size_t bytes) -> void* {
        void* p = base + off;
        off += (bytes + 255) & ~(size_t)255;
        return p;
    };
    int* outd   = (int*)alloc((size_t)N * 4);
    int* ind    = (int*)alloc((size_t)N * 4);
    int* rowp   = (int*)alloc((size_t)(N + 1) * 4);
    int* csr    = (int*)alloc((size_t)E * 4);
    unsigned* ebuf = (unsigned*)alloc((size_t)E * 4);
    int* didx   = (int*)alloc((size_t)N * 4);
    float* cs   = (float*)alloc((size_t)N * 4);
    float* cd   = (float*)alloc((size_t)N * 4);
    float* WF   = (float*)alloc((size_t)512 * 128 * 4);
    float* cb   = (float*)alloc((size_t)128 * 4);
    int* blocksum = (int*)alloc(128 * 4);
    int* blockoff = (int*)alloc(128 * 4);
    int* bcur     = (int*)alloc(128 * 4);
    unsigned short* wt_hi  = (unsigned short*)alloc((size_t)128 * 640 * 2);
    unsigned short* wt_lo  = (unsigned short*)alloc((size_t)128 * 640 * 2);
    unsigned short* w2t_hi = (unsigned short*)alloc((size_t)64 * 128 * 2);
    unsigned short* w2t_lo = (unsigned short*)alloc((size_t)64 * 128 * 2);
    unsigned short* h1 = (unsigned short*)alloc((size_t)N * 128 * 2);
    float* yb   = (float*)alloc((size_t)N * 128 * 4);
    unsigned short* h2 = h1;   // h1 dead after k_agg1; reuse
    float* outp = (float*)d_out;

    hipMemsetAsync(outd, 0, (size_t)N * 4, stream);
    hipMemsetAsync(ind, 0, (size_t)N * 4, stream);

    int eb = (E + 255) / 256;
    int nb = (N + 255) / 256;
    int mb = (N + 127) / 128;
    int nscan = (N + 1023) / 1024;   // buckets too; <=128 for N<=131072

    k_degrees<<<eb, 256, 0, stream>>>(src, dst, E, outd, ind);
    k_norms<<<nb, 256, 0, stream>>>(outd, ind, N, cs, cd, didx);
    k_scan_part<<<nscan, 256, 0, stream>>>(ind, N, blocksum);
    k_scan_mid<<<1, 128, 0, stream>>>(blocksum, nscan, blockoff, rowp, N);
    k_scan_add<<<nscan, 256, 0, stream>>>(ind, N, blockoff, rowp);
    k_binit<<<1, 128, 0, stream>>>(rowp, bcur, nscan);
    k_cscatter<<<(E + 4095) / 4096, 256, 0, stream>>>(src, dst, E, bcur, ebuf, nscan);
    k_cbuild<<<nscan, 512, 0, stream>>>(ebuf, rowp, csr, N);
    k_wf<<<256, 256, 0, stream>>>(projW, W1, WF);
    k_cb<<<1, 128, 0, stream>>>(projb, W1, cb);
    k_wt1<<<320, 256, 0, stream>>>(WF, W1, wt_hi, wt_lo);
    k_wt2<<<32, 256, 0, stream>>>(W2, w2t_hi, w2t_lo);
    k_h1<<<mb, 256, 0, stream>>>(logits, features, deg_table, didx, wt_hi, wt_lo, cb, cs, h1, N);
    k_agg1<<<(N + 3) / 4, 256, 0, stream>>>(h1, rowp, csr, cd, b1, yb, N);
    k_h2<<<mb, 256, 0, stream>>>(yb, w2t_hi, w2t_lo, cs, h2, N);
    k_agg2<<<(N + 7) / 8, 256, 0, stream>>>(h2, rowp, csr, cd, b2, outp, N);
}

// Round 8
// 345.926 us; speedup vs baseline: 4.6626x; 1.2669x over previous
//
#include <hip/hip_runtime.h>
#include <cstdint>
#include <cstddef>

// ---------------------------------------------------------------------------
// GCN forward, MFMA edition:
//   bucketed graph preprocessing (NO scattered global atomics anywhere):
//     bcount (per-bucket edge histograms) -> bscan -> scatter2 (edges into
//     dst-bucket ebuf + src-bucket sbuf) -> bucket_dst (ind+rowp+csr per
//     1024-node bucket, all LDS) -> bucket_src (outd) -> norms
//   -> WF=projW@W1mid -> WT hi/lo bf16 -> h1 = cs*(x@W1+cb) [split-bf16
//   3-term MFMA] -> agg1 -> y=relu(...) -> h2 = cs*(y@W2) -> agg2 -> out
// Split trick: a = a_hi + a_lo (bf16 trunc + bf16 residual);
// D = ahi*bhi + alo*bhi + ahi*blo -> only O(2^-17) rel. terms dropped.
// R6/R7 lesson (twice): scattered 4B atomic stores across 8 non-coherent XCD
// L2s cost ~64B HBM writeback per op (degrees: 100MB for 0.8MB of data).
// Fix: bucket edges so each 1024-node range's data is built by ONE block in
// LDS and written contiguously. Bucket regions need only per-bucket counts.
// R4 lesson: don't cap VGPRs below acc needs (spill -> scratch traffic).
// LDS swizzle: chunk' = chunk ^ (row&3) on 16B chunks, row stride 32 shorts.
// ---------------------------------------------------------------------------

typedef short short8 __attribute__((ext_vector_type(8)));
typedef float f32x4 __attribute__((ext_vector_type(4)));

__device__ __forceinline__ unsigned short f2bf(float f) {
    unsigned u = __float_as_uint(f);
    u += 0x7fff + ((u >> 16) & 1);   // RNE
    return (unsigned short)(u >> 16);
}
__device__ __forceinline__ float bf2f(unsigned short s) {
    return __uint_as_float(((unsigned)s) << 16);
}

__device__ __forceinline__ void split_f4(float4 a, float4 b, short8& hv, short8& lv) {
    float f[8] = {a.x, a.y, a.z, a.w, b.x, b.y, b.z, b.w};
#pragma unroll
    for (int i = 0; i < 8; ++i) {
        unsigned u = __float_as_uint(f[i]);
        hv[i] = (short)(u >> 16);
        float r = f[i] - __uint_as_float(u & 0xffff0000u);
        lv[i] = (short)(__float_as_uint(r) >> 16);
    }
}

// ---- bucket preprocessing (buckets = 1024-node ranges, nb <= 128) ----

// per-block LDS histograms -> global per-bucket edge counts (dst and src)
__global__ __launch_bounds__(256) void k_bcount(
    const int* __restrict__ src, const int* __restrict__ dst, int E,
    int* __restrict__ dcount, int* __restrict__ scount)
{
    __shared__ int dh[128], sh_[128];
    int t = threadIdx.x;
    if (t < 128) { dh[t] = 0; sh_[t] = 0; }
    __syncthreads();
    int e0 = blockIdx.x * 4096;
#pragma unroll
    for (int i = 0; i < 16; ++i) {
        int idx = e0 + t + i * 256;
        if (idx < E) {
            atomicAdd(&dh[dst[idx] >> 10], 1);
            atomicAdd(&sh_[src[idx] >> 10], 1);
        }
    }
    __syncthreads();
    if (t < 128) {
        if (dh[t]) atomicAdd(&dcount[t], dh[t]);
        if (sh_[t]) atomicAdd(&scount[t], sh_[t]);
    }
}

// scan the two 128-count arrays -> region offsets + cursors
__global__ __launch_bounds__(128) void k_bscan(
    const int* __restrict__ dcount, const int* __restrict__ scount, int nb,
    int E, int* __restrict__ dboff, int* __restrict__ sboff,
    int* __restrict__ dcur, int* __restrict__ scur,
    int* __restrict__ rowp, int N)
{
    __shared__ int sh[128];
    int t = threadIdx.x;
    int v = (t < nb) ? dcount[t] : 0;
    sh[t] = v;
    __syncthreads();
    for (int off = 1; off < 128; off <<= 1) {
        int x = (t >= off) ? sh[t - off] : 0;
        __syncthreads();
        sh[t] += x;
        __syncthreads();
    }
    if (t < nb) { int e = sh[t] - v; dboff[t] = e; dcur[t] = e; }
    __syncthreads();
    int v2 = (t < nb) ? scount[t] : 0;
    sh[t] = v2;
    __syncthreads();
    for (int off = 1; off < 128; off <<= 1) {
        int x = (t >= off) ? sh[t - off] : 0;
        __syncthreads();
        sh[t] += x;
        __syncthreads();
    }
    if (t < nb) { int e = sh[t] - v2; sboff[t] = e; scur[t] = e; }
    if (t == 0) rowp[N] = E;
}

// scatter edges into dst-bucket regions of ebuf AND src-bucket regions of
// sbuf; block-privatized reservations (one global atomic per block-bucket).
__global__ __launch_bounds__(256) void k_scatter2(
    const int* __restrict__ src, const int* __restrict__ dst, int E,
    int* __restrict__ dcur, int* __restrict__ scur,
    unsigned* __restrict__ ebuf, unsigned short* __restrict__ sbuf, int nb)
{
    __shared__ int dh[128], dbase[128], sh_[128], sbase[128];
    int t = threadIdx.x;
    int e0 = blockIdx.x * 4096;
    if (t < 128) { dh[t] = 0; sh_[t] = 0; }
    __syncthreads();
    int s_[16], d_[16];
#pragma unroll
    for (int i = 0; i < 16; ++i) {
        int idx = e0 + t + i * 256;
        if (idx < E) {
            s_[i] = src[idx];
            d_[i] = dst[idx];
            atomicAdd(&dh[d_[i] >> 10], 1);
            atomicAdd(&sh_[s_[i] >> 10], 1);
        } else d_[i] = -1;
    }
    __syncthreads();
    if (t < nb) {
        if (dh[t]) dbase[t] = atomicAdd(&dcur[t], dh[t]);
        if (sh_[t]) sbase[t] = atomicAdd(&scur[t], sh_[t]);
    }
    __syncthreads();
    if (t < 128) { dh[t] = 0; sh_[t] = 0; }
    __syncthreads();
#pragma unroll
    for (int i = 0; i < 16; ++i) {
        if (d_[i] >= 0) {
            int b = d_[i] >> 10;
            int p = dbase[b] + atomicAdd(&dh[b], 1);
            ebuf[p] = (unsigned)s_[i] | ((unsigned)(d_[i] & 1023) << 17);
            int bs = s_[i] >> 10;
            int q = sbase[bs] + atomicAdd(&sh_[bs], 1);
            sbuf[q] = (unsigned short)(s_[i] & 1023);
        }
    }
}

// one block per bucket: count in-degrees, scan -> rowp, sort edges -> csr
__global__ __launch_bounds__(512) void k_bucket_dst(
    const unsigned* __restrict__ ebuf, const int* __restrict__ dboff,
    const int* __restrict__ dcount, int* __restrict__ ind,
    int* __restrict__ rowp, int* __restrict__ csr, int N)
{
    __shared__ int cnt[1024];
    __shared__ int sums[512];
    int b = blockIdx.x;
    int nb0 = b << 10;
    int ncnt = min(1024, N - nb0);
    int t = threadIdx.x;
    cnt[t] = 0; cnt[t + 512] = 0;
    __syncthreads();
    int lo = dboff[b], hi = lo + dcount[b];
    for (int idx = lo + t; idx < hi; idx += 512)
        atomicAdd(&cnt[ebuf[idx] >> 17], 1);
    __syncthreads();
    int c0 = cnt[2 * t], c1 = cnt[2 * t + 1];
    sums[t] = c0 + c1;
    __syncthreads();
    for (int off = 1; off < 512; off <<= 1) {
        int x = (t >= off) ? sums[t - off] : 0;
        __syncthreads();
        sums[t] += x;
        __syncthreads();
    }
    int excl = sums[t] - (c0 + c1);
    int r0 = lo + excl, r1 = r0 + c0;
    if (2 * t < ncnt)     { rowp[nb0 + 2 * t] = r0;     ind[nb0 + 2 * t] = c0; }
    if (2 * t + 1 < ncnt) { rowp[nb0 + 2 * t + 1] = r1; ind[nb0 + 2 * t + 1] = c1; }
    __syncthreads();
    cnt[2 * t] = r0; cnt[2 * t + 1] = r1;   // cursors (absolute)
    __syncthreads();
    for (int idx = lo + t; idx < hi; idx += 512) {
        unsigned e = ebuf[idx];
        int p = atomicAdd(&cnt[e >> 17], 1);
        csr[p] = (int)(e & 0x1FFFF);
    }
}

// one block per bucket: count out-degrees -> outd (contiguous write)
__global__ __launch_bounds__(512) void k_bucket_src(
    const unsigned short* __restrict__ sbuf, const int* __restrict__ sboff,
    const int* __restrict__ scount, int* __restrict__ outd, int N)
{
    __shared__ int cnt[1024];
    int b = blockIdx.x;
    int nb0 = b << 10;
    int ncnt = min(1024, N - nb0);
    int t = threadIdx.x;
    cnt[t] = 0; cnt[t + 512] = 0;
    __syncthreads();
    int lo = sboff[b], hi = lo + scount[b];
    for (int idx = lo + t; idx < hi; idx += 512)
        atomicAdd(&cnt[sbuf[idx]], 1);
    __syncthreads();
    if (t < ncnt) outd[nb0 + t] = cnt[t];
    if (t + 512 < ncnt) outd[nb0 + t + 512] = cnt[t + 512];
}

__global__ __launch_bounds__(256) void k_norms(
    const int* __restrict__ outd, const int* __restrict__ ind, int N,
    float* __restrict__ cs, float* __restrict__ cd, int* __restrict__ didx)
{
    int i = blockIdx.x * 256 + threadIdx.x;
    if (i < N) {
        int od = outd[i], id = ind[i];
        cs[i] = rsqrtf((float)(od > 0 ? od : 1));
        cd[i] = rsqrtf((float)(id > 0 ? id : 1));
        int d = od + id;
        didx[i] = d > 511 ? 511 : d;
    }
}

// WF[k][j] = sum_m projW[k][m] * W1[64+m][j]   (512x128 fp32)
__global__ __launch_bounds__(256) void k_wf(
    const float* __restrict__ projW, const float* __restrict__ W1,
    float* __restrict__ WF)
{
    int idx = blockIdx.x * 256 + threadIdx.x;
    int k = idx >> 7, j = idx & 127;
    const float* a = projW + (size_t)k * 128;
    float s = 0.f;
#pragma unroll 8
    for (int m = 0; m < 128; ++m) s = fmaf(a[m], W1[(size_t)(64 + m) * 128 + j], s);
    WF[idx] = s;
}

__global__ void k_cb(const float* __restrict__ projb, const float* __restrict__ W1,
                     float* __restrict__ cb)
{
    int j = threadIdx.x;
    float s = 0.f;
    for (int m = 0; m < 128; ++m) s = fmaf(projb[m], W1[(size_t)(64 + m) * 128 + j], s);
    cb[j] = s;
}

// WT[j][k] split hi/lo bf16; k<512: WF, k<576: W1[0:64], else W1[192:256]
__global__ __launch_bounds__(256) void k_wt1(
    const float* __restrict__ WF, const float* __restrict__ W1,
    unsigned short* __restrict__ wt_hi, unsigned short* __restrict__ wt_lo)
{
    int idx = blockIdx.x * 256 + threadIdx.x;   // 128*640
    int j = idx / 640, k = idx - j * 640;
    float v;
    if (k < 512) v = WF[(size_t)k * 128 + j];
    else if (k < 576) v = W1[(size_t)(k - 512) * 128 + j];
    else v = W1[(size_t)(192 + k - 576) * 128 + j];
    unsigned short h = f2bf(v);
    wt_hi[idx] = h;
    float r = v - bf2f(h);
    wt_lo[idx] = (unsigned short)(__float_as_uint(r) >> 16);
}

__global__ __launch_bounds__(256) void k_wt2(
    const float* __restrict__ W2,
    unsigned short* __restrict__ w2t_hi, unsigned short* __restrict__ w2t_lo)
{
    int idx = blockIdx.x * 256 + threadIdx.x;   // 64*128
    int j = idx >> 7, k = idx & 127;
    float v = W2[(size_t)k * 64 + j];
    unsigned short h = f2bf(v);
    w2t_hi[idx] = h;
    float r = v - bf2f(h);
    w2t_lo[idx] = (unsigned short)(__float_as_uint(r) >> 16);
}

// ---- k_h1: 128x128 tile, 4 waves (2x2), wave=64x64 (4x4 frags of 16x16),
// K = 20 steps x 32, split-bf16 3-term MFMA.
// LDS: [buf][row][k], row stride 32 shorts, 16B-chunk XOR swizzle
// chunk' = chunk ^ (row&3). Double-buffered, one barrier per K-step.
__global__ __launch_bounds__(256, 2) void k_h1(
    const float* __restrict__ logits, const float* __restrict__ features,
    const float* __restrict__ deg_table, const int* __restrict__ didx,
    const unsigned short* __restrict__ wt_hi, const unsigned short* __restrict__ wt_lo,
    const float* __restrict__ cb, const float* __restrict__ cs,
    unsigned short* __restrict__ h1, int N)
{
    constexpr int NT = 20;
    __shared__ __align__(16) short Ah[2][128 * 32];
    __shared__ __align__(16) short Al[2][128 * 32];
    __shared__ __align__(16) short Bh[2][128 * 32];
    __shared__ __align__(16) short Bl[2][128 * 32];
    int tid = threadIdx.x;
    int i0 = blockIdx.x * 128;
    int sr = tid >> 1, shh = tid & 1;
    int snode = i0 + sr; if (snode >= N) snode = N - 1;
    int sdidx = didx[snode];
    int wo0 = sr * 32 + ((shh    ) ^ (sr & 3)) * 8;
    int wo1 = sr * 32 + ((shh + 2) ^ (sr & 3)) * 8;
    int lane = tid & 63, w = tid >> 6;
    int wr = w >> 1, wc = w & 1;
    int fr = lane & 15, kg = lane >> 4;
    int aoff = (wr * 64 + fr) * 32 + (kg ^ (fr & 3)) * 8;
    int boff = (wc * 64 + fr) * 32 + (kg ^ (fr & 3)) * 8;

    f32x4 acc[4][4];
#pragma unroll
    for (int ri = 0; ri < 4; ++ri)
#pragma unroll
        for (int ci = 0; ci < 4; ++ci) acc[ri][ci] = (f32x4)0.f;

    float4 fa0, fa1, fa2, fa3;
    uint4 pbh0, pbh1, pbl0, pbl1;

    auto loadT = [&](int t) {
        const float* ap;
        if (t < 16)      ap = features  + (size_t)snode * 512 + t * 32;
        else if (t < 18) ap = logits    + (size_t)snode * 64 + (t - 16) * 32;
        else             ap = deg_table + (size_t)sdidx * 64 + (t - 18) * 32;
        ap += shh * 8;
        fa0 = *(const float4*)(ap);
        fa1 = *(const float4*)(ap + 4);
        fa2 = *(const float4*)(ap + 16);
        fa3 = *(const float4*)(ap + 20);
        const unsigned short* bh = wt_hi + (size_t)sr * 640 + t * 32 + shh * 8;
        const unsigned short* bl = wt_lo + (size_t)sr * 640 + t * 32 + shh * 8;
        pbh0 = *(const uint4*)(bh);
        pbh1 = *(const uint4*)(bh + 16);
        pbl0 = *(const uint4*)(bl);
        pbl1 = *(const uint4*)(bl + 16);
    };
    auto writeT = [&](int buf) {
        short8 h0, l0, h1v, l1v;
        split_f4(fa0, fa1, h0, l0);
        split_f4(fa2, fa3, h1v, l1v);
        *(short8*)&Ah[buf][wo0] = h0;   *(short8*)&Ah[buf][wo1] = h1v;
        *(short8*)&Al[buf][wo0] = l0;   *(short8*)&Al[buf][wo1] = l1v;
        *(uint4*)&Bh[buf][wo0] = pbh0;  *(uint4*)&Bh[buf][wo1] = pbh1;
        *(uint4*)&Bl[buf][wo0] = pbl0;  *(uint4*)&Bl[buf][wo1] = pbl1;
    };

    loadT(0);
    writeT(0);
    __syncthreads();
    for (int t = 0; t < NT; ++t) {
        if (t + 1 < NT) loadT(t + 1);
        int cbuf = t & 1;
        short8 ah[4], al[4];
#pragma unroll
        for (int ri = 0; ri < 4; ++ri) {
            ah[ri] = *(const short8*)&Ah[cbuf][aoff + ri * 512];
            al[ri] = *(const short8*)&Al[cbuf][aoff + ri * 512];
        }
#pragma unroll
        for (int ci = 0; ci < 4; ++ci) {
            short8 bh = *(const short8*)&Bh[cbuf][boff + ci * 512];
            short8 bl = *(const short8*)&Bl[cbuf][boff + ci * 512];
#pragma unroll
            for (int ri = 0; ri < 4; ++ri) {
                acc[ri][ci] = __builtin_amdgcn_mfma_f32_16x16x32_bf16(ah[ri], bh, acc[ri][ci], 0, 0, 0);
                acc[ri][ci] = __builtin_amdgcn_mfma_f32_16x16x32_bf16(al[ri], bh, acc[ri][ci], 0, 0, 0);
                acc[ri][ci] = __builtin_amdgcn_mfma_f32_16x16x32_bf16(ah[ri], bl, acc[ri][ci], 0, 0, 0);
            }
        }
        if (t + 1 < NT) writeT((t + 1) & 1);
        __syncthreads();
    }

    float cbv[4];
#pragma unroll
    for (int ci = 0; ci < 4; ++ci) cbv[ci] = cb[wc * 64 + ci * 16 + fr];
#pragma unroll
    for (int ri = 0; ri < 4; ++ri) {
#pragma unroll
        for (int j = 0; j < 4; ++j) {
            int row = i0 + wr * 64 + ri * 16 + kg * 4 + j;
            if (row < N) {
                float scv = cs[row];
#pragma unroll
                for (int ci = 0; ci < 4; ++ci) {
                    int col = wc * 64 + ci * 16 + fr;
                    h1[(size_t)row * 128 + col] = f2bf(scv * (acc[ri][ci][j] + cbv[ci]));
                }
            }
        }
    }
}

// Layer-1 aggregation: y[i] = relu( (sum_{e: dst=i} h1[src_e]) * cd[i] + b1 )
__global__ __launch_bounds__(256) void k_agg1(
    const unsigned short* __restrict__ h1, const int* __restrict__ rowp,
    const int* __restrict__ csr, const float* __restrict__ cd,
    const float* __restrict__ b1, float* __restrict__ y, int N)
{
    int i = blockIdx.x * 4 + (threadIdx.x >> 6);
    if (i >= N) return;
    int lane = threadIdx.x & 63;
    int s0 = rowp[i], s1 = rowp[i + 1];
    float ax = 0.f, ay = 0.f;
    int e = s0;
    for (; e + 8 <= s1; e += 8) {
        unsigned u0 = *(const unsigned*)(h1 + (size_t)csr[e + 0] * 128 + lane * 2);
        unsigned u1 = *(const unsigned*)(h1 + (size_t)csr[e + 1] * 128 + lane * 2);
        unsigned u2 = *(const unsigned*)(h1 + (size_t)csr[e + 2] * 128 + lane * 2);
        unsigned u3 = *(const unsigned*)(h1 + (size_t)csr[e + 3] * 128 + lane * 2);
        unsigned u4 = *(const unsigned*)(h1 + (size_t)csr[e + 4] * 128 + lane * 2);
        unsigned u5 = *(const unsigned*)(h1 + (size_t)csr[e + 5] * 128 + lane * 2);
        unsigned u6 = *(const unsigned*)(h1 + (size_t)csr[e + 6] * 128 + lane * 2);
        unsigned u7 = *(const unsigned*)(h1 + (size_t)csr[e + 7] * 128 + lane * 2);
        ax += ((__uint_as_float(u0 << 16) + __uint_as_float(u1 << 16)) +
               (__uint_as_float(u2 << 16) + __uint_as_float(u3 << 16))) +
              ((__uint_as_float(u4 << 16) + __uint_as_float(u5 << 16)) +
               (__uint_as_float(u6 << 16) + __uint_as_float(u7 << 16)));
        ay += ((__uint_as_float(u0 & 0xffff0000u) + __uint_as_float(u1 & 0xffff0000u)) +
               (__uint_as_float(u2 & 0xffff0000u) + __uint_as_float(u3 & 0xffff0000u))) +
              ((__uint_as_float(u4 & 0xffff0000u) + __uint_as_float(u5 & 0xffff0000u)) +
               (__uint_as_float(u6 & 0xffff0000u) + __uint_as_float(u7 & 0xffff0000u)));
    }
    for (; e < s1; ++e) {
        unsigned u = *(const unsigned*)(h1 + (size_t)csr[e] * 128 + lane * 2);
        ax += __uint_as_float(u << 16);
        ay += __uint_as_float(u & 0xffff0000u);
    }
    float cdi = cd[i];
    float2 o;
    o.x = fmaxf(fmaf(ax, cdi, b1[lane * 2 + 0]), 0.f);
    o.y = fmaxf(fmaf(ay, cdi, b1[lane * 2 + 1]), 0.f);
    *(float2*)(y + (size_t)i * 128 + lane * 2) = o;
}

// ---- k_h2: h2 = cs*(y@W2), 128x64 tile, wave=64x32 (4x2 frags), K=4x32.
__global__ __launch_bounds__(256, 2) void k_h2(
    const float* __restrict__ y,
    const unsigned short* __restrict__ w2t_hi, const unsigned short* __restrict__ w2t_lo,
    const float* __restrict__ cs, unsigned short* __restrict__ h2, int N)
{
    constexpr int NT = 4;
    __shared__ __align__(16) short Ah[2][128 * 32];
    __shared__ __align__(16) short Al[2][128 * 32];
    __shared__ __align__(16) short Bh[2][64 * 32];
    __shared__ __align__(16) short Bl[2][64 * 32];
    int tid = threadIdx.x;
    int i0 = blockIdx.x * 128;
    int sr = tid >> 1, shh = tid & 1;
    int snode = i0 + sr; if (snode >= N) snode = N - 1;
    const float* abase = y + (size_t)snode * 128 + shh * 8;
    int awo0 = sr * 32 + ((shh    ) ^ (sr & 3)) * 8;
    int awo1 = sr * 32 + ((shh + 2) ^ (sr & 3)) * 8;
    int brow_s = tid >> 2, bc = tid & 3;
    int bwo = brow_s * 32 + (bc ^ (brow_s & 3)) * 8;
    int lane = tid & 63, w = tid >> 6;
    int wr = w >> 1, wc = w & 1;
    int fr = lane & 15, kg = lane >> 4;
    int aoff = (wr * 64 + fr) * 32 + (kg ^ (fr & 3)) * 8;
    int boff = (wc * 32 + fr) * 32 + (kg ^ (fr & 3)) * 8;

    f32x4 acc[4][2];
#pragma unroll
    for (int ri = 0; ri < 4; ++ri)
#pragma unroll
        for (int ci = 0; ci < 2; ++ci) acc[ri][ci] = (f32x4)0.f;

    float4 fa0, fa1, fa2, fa3;
    uint4 pbh0, pbl0;

    auto loadT = [&](int t) {
        const float* ap = abase + t * 32;
        fa0 = *(const float4*)(ap);
        fa1 = *(const float4*)(ap + 4);
        fa2 = *(const float4*)(ap + 16);
        fa3 = *(const float4*)(ap + 20);
        pbh0 = *(const uint4*)(w2t_hi + (size_t)brow_s * 128 + t * 32 + bc * 8);
        pbl0 = *(const uint4*)(w2t_lo + (size_t)brow_s * 128 + t * 32 + bc * 8);
    };
    auto writeT = [&](int buf) {
        short8 h0, l0, h1v, l1v;
        split_f4(fa0, fa1, h0, l0);
        split_f4(fa2, fa3, h1v, l1v);
        *(short8*)&Ah[buf][awo0] = h0;  *(short8*)&Ah[buf][awo1] = h1v;
        *(short8*)&Al[buf][awo0] = l0;  *(short8*)&Al[buf][awo1] = l1v;
        *(uint4*)&Bh[buf][bwo] = pbh0;
        *(uint4*)&Bl[buf][bwo] = pbl0;
    };

    loadT(0);
    writeT(0);
    __syncthreads();
    for (int t = 0; t < NT; ++t) {
        if (t + 1 < NT) loadT(t + 1);
        int cbuf = t & 1;
        short8 ah[4], al[4];
#pragma unroll
        for (int ri = 0; ri < 4; ++ri) {
            ah[ri] = *(const short8*)&Ah[cbuf][aoff + ri * 512];
            al[ri] = *(const short8*)&Al[cbuf][aoff + ri * 512];
        }
#pragma unroll
        for (int ci = 0; ci < 2; ++ci) {
            short8 bh = *(const short8*)&Bh[cbuf][boff + ci * 512];
            short8 bl = *(const short8*)&Bl[cbuf][boff + ci * 512];
#pragma unroll
            for (int ri = 0; ri < 4; ++ri) {
                acc[ri][ci] = __builtin_amdgcn_mfma_f32_16x16x32_bf16(ah[ri], bh, acc[ri][ci], 0, 0, 0);
                acc[ri][ci] = __builtin_amdgcn_mfma_f32_16x16x32_bf16(al[ri], bh, acc[ri][ci], 0, 0, 0);
                acc[ri][ci] = __builtin_amdgcn_mfma_f32_16x16x32_bf16(ah[ri], bl, acc[ri][ci], 0, 0, 0);
            }
        }
        if (t + 1 < NT) writeT((t + 1) & 1);
        __syncthreads();
    }

#pragma unroll
    for (int ri = 0; ri < 4; ++ri) {
#pragma unroll
        for (int j = 0; j < 4; ++j) {
            int row = i0 + wr * 64 + ri * 16 + kg * 4 + j;
            if (row < N) {
                float scv = cs[row];
#pragma unroll
                for (int ci = 0; ci < 2; ++ci) {
                    int col = wc * 32 + ci * 16 + fr;
                    h2[(size_t)row * 64 + col] = f2bf(scv * acc[ri][ci][j]);
                }
            }
        }
    }
}

// Layer-2 aggregation: out[i] = (sum h2[src_e]) * cd[i] + b2
__global__ __launch_bounds__(256) void k_agg2(
    const unsigned short* __restrict__ h2, const int* __restrict__ rowp,
    const int* __restrict__ csr, const float* __restrict__ cd,
    const float* __restrict__ b2, float* __restrict__ out, int N)
{
    int i = blockIdx.x * 8 + (threadIdx.x >> 5);
    if (i >= N) return;
    int lane = threadIdx.x & 31;
    int s0 = rowp[i], s1 = rowp[i + 1];
    float ax = 0.f, ay = 0.f;
    int e = s0;
    for (; e + 8 <= s1; e += 8) {
        unsigned u0 = *(const unsigned*)(h2 + (size_t)csr[e + 0] * 64 + lane * 2);
        unsigned u1 = *(const unsigned*)(h2 + (size_t)csr[e + 1] * 64 + lane * 2);
        unsigned u2 = *(const unsigned*)(h2 + (size_t)csr[e + 2] * 64 + lane * 2);
        unsigned u3 = *(const unsigned*)(h2 + (size_t)csr[e + 3] * 64 + lane * 2);
        unsigned u4 = *(const unsigned*)(h2 + (size_t)csr[e + 4] * 64 + lane * 2);
        unsigned u5 = *(const unsigned*)(h2 + (size_t)csr[e + 5] * 64 + lane * 2);
        unsigned u6 = *(const unsigned*)(h2 + (size_t)csr[e + 6] * 64 + lane * 2);
        unsigned u7 = *(const unsigned*)(h2 + (size_t)csr[e + 7] * 64 + lane * 2);
        ax += ((__uint_as_float(u0 << 16) + __uint_as_float(u1 << 16)) +
               (__uint_as_float(u2 << 16) + __uint_as_float(u3 << 16))) +
              ((__uint_as_float(u4 << 16) + __uint_as_float(u5 << 16)) +
               (__uint_as_float(u6 << 16) + __uint_as_float(u7 << 16)));
        ay += ((__uint_as_float(u0 & 0xffff0000u) + __uint_as_float(u1 & 0xffff0000u)) +
               (__uint_as_float(u2 & 0xffff0000u) + __uint_as_float(u3 & 0xffff0000u))) +
              ((__uint_as_float(u4 & 0xffff0000u) + __uint_as_float(u5 & 0xffff0000u)) +
               (__uint_as_float(u6 & 0xffff0000u) + __uint_as_float(u7 & 0xffff0000u)));
    }
    for (; e < s1; ++e) {
        unsigned u = *(const unsigned*)(h2 + (size_t)csr[e] * 64 + lane * 2);
        ax += __uint_as_float(u << 16);
        ay += __uint_as_float(u & 0xffff0000u);
    }
    float cdi = cd[i];
    float2 o;
    o.x = fmaf(ax, cdi, b2[lane * 2 + 0]);
    o.y = fmaf(ay, cdi, b2[lane * 2 + 1]);
    *(float2*)(out + (size_t)i * 64 + lane * 2) = o;
}

extern "C" void kernel_launch(void* const* d_in, const int* in_sizes, int n_in,
                              void* d_out, int out_size, void* d_ws, size_t ws_size,
                              hipStream_t stream)
{
    const int* src = (const int*)d_in[0];
    const int* dst = (const int*)d_in[1];
    const float* logits = (const float*)d_in[2];
    const float* features = (const float*)d_in[3];
    const float* projW = (const float*)d_in[4];
    const float* projb = (const float*)d_in[5];
    const float* deg_table = (const float*)d_in[6];
    const float* W1 = (const float*)d_in[7];
    const float* b1 = (const float*)d_in[8];
    const float* W2 = (const float*)d_in[9];
    const float* b2 = (const float*)d_in[10];
    const int E = in_sizes[0];
    const int N = in_sizes[2] / 64;

    char* base = (char*)d_ws;
    size_t off = 0;
    auto alloc = [&](size_t bytes) -> void* {
        void* p = base + off;
        off += (bytes + 255) & ~(size_t)255;
        return p;
    };
    int* outd   = (int*)alloc((size_t)N * 4);
    int* ind    = (int*)alloc((size_t)N * 4);
    int* rowp   = (int*)alloc((size_t)(N + 1) * 4);
    int* csr    = (int*)alloc((size_t)E * 4);
    unsigned* ebuf = (unsigned*)alloc((size_t)E * 4);
    unsigned short* sbuf = (unsigned short*)alloc((size_t)E * 2);
    int* didx   = (int*)alloc((size_t)N * 4);
    float* cs   = (float*)alloc((size_t)N * 4);
    float* cd   = (float*)alloc((size_t)N * 4);
    float* WF   = (float*)alloc((size_t)512 * 128 * 4);
    float* cb   = (float*)alloc((size_t)128 * 4);
    int* dcount = (int*)alloc(128 * 4);
    int* scount = (int*)alloc(128 * 4);
    int* dboff  = (int*)alloc(128 * 4);
    int* sboff  = (int*)alloc(128 * 4);
    int* dcur   = (int*)alloc(128 * 4);
    int* scur   = (int*)alloc(128 * 4);
    unsigned short* wt_hi  = (unsigned short*)alloc((size_t)128 * 640 * 2);
    unsigned short* wt_lo  = (unsigned short*)alloc((size_t)128 * 640 * 2);
    unsigned short* w2t_hi = (unsigned short*)alloc((size_t)64 * 128 * 2);
    unsigned short* w2t_lo = (unsigned short*)alloc((size_t)64 * 128 * 2);
    unsigned short* h1 = (unsigned short*)alloc((size_t)N * 128 * 2);
    float* yb   = (float*)alloc((size_t)N * 128 * 4);
    unsigned short* h2 = h1;   // h1 dead after k_agg1; reuse
    float* outp = (float*)d_out;

    hipMemsetAsync(dcount, 0, 128 * 4, stream);
    hipMemsetAsync(scount, 0, 128 * 4, stream);

    int nb = (N + 255) / 256;
    int mb = (N + 127) / 128;
    int ebk = (E + 4095) / 4096;
    int nbuck = (N + 1023) / 1024;   // <=128 for N<=131072

    k_bcount<<<ebk, 256, 0, stream>>>(src, dst, E, dcount, scount);
    k_bscan<<<1, 128, 0, stream>>>(dcount, scount, nbuck, E, dboff, sboff, dcur, scur, rowp, N);
    k_scatter2<<<ebk, 256, 0, stream>>>(src, dst, E, dcur, scur, ebuf, sbuf, nbuck);
    k_bucket_dst<<<nbuck, 512, 0, stream>>>(ebuf, dboff, dcount, ind, rowp, csr, N);
    k_bucket_src<<<nbuck, 512, 0, stream>>>(sbuf, sboff, scount, outd, N);
    k_norms<<<nb, 256, 0, stream>>>(outd, ind, N, cs, cd, didx);
    k_wf<<<256, 256, 0, stream>>>(projW, W1, WF);
    k_cb<<<1, 128, 0, stream>>>(projb, W1, cb);
    k_wt1<<<320, 256, 0, stream>>>(WF, W1, wt_hi, wt_lo);
    k_wt2<<<32, 256, 0, stream>>>(W2, w2t_hi, w2t_lo);
    k_h1<<<mb, 256, 0, stream>>>(logits, features, deg_table, didx, wt_hi, wt_lo, cb, cs, h1, N);
    k_agg1<<<(N + 3) / 4, 256, 0, stream>>>(h1, rowp, csr, cd, b1, yb, N);
    k_h2<<<mb, 256, 0, stream>>>(yb, w2t_hi, w2t_lo, cs, h2, N);
    k_agg2<<<(N + 7) / 8, 256, 0, stream>>>(h2, rowp, csr, cd, b2, outp, N);
}